// Round 1
// baseline (4441.499 us; speedup 1.0000x reference)
//
#include <hip/hip_runtime.h>
#include <math.h>

// Problem constants
#define BB 2048
#define LL 100
#define FF 64
#define EE 256
#define DD 256
#define NOUT 3

#define COMP(v, i) ((i) == 0 ? (v).x : (i) == 1 ? (v).y : (i) == 2 ? (v).z : (v).w)

__device__ __forceinline__ float sigmoidf_(float x) {
    return 1.0f / (1.0f + expf(-x));
}
// tanh via identity 1 - 2/(1+e^{2x}); ~2e-7 abs fp32 error, saturates correctly.
__device__ __forceinline__ float tanhf_(float x) {
    return 1.0f - 2.0f / (1.0f + expf(2.0f * x));
}

// ---------------------------------------------------------------------------
// Persistent encoder, 1024-thread blocks (16 waves -> 4 waves/SIMD at 1
// block/CU) with 4-way k-split. grid 256; block owns 8 rows for all 100 steps.
//  - attention: waves 0..7 (w = row), lane = col; coalesced scalar Wa loads.
//  - gates: thread = (quarter q = tid>>8, ct = tid&255) -> cols ct*4..+3,
//    k-chunks [q*20, q*20+20) of the stacked [Wi;Wh] (320 k total). Weights
//    read directly from row-major Wi/Wh as lane-contiguous float4 (1KB
//    coalesced per wave-inst). Per-CU weight traffic unchanged vs round 10
//    (same one block reads them once per step) -- only occupancy changes.
//  - partial combine: two phases through gate_s[2] (q0/q1 then q2/q3),
//    epilogue waves hold phase-1 partials in 16 regs. 4 barriers/step.
//  - epilogue: wave-local (w<8, lane -> 4 units of row w), c in registers.
// ---------------------------------------------------------------------------
__global__ __launch_bounds__(1024) void enc_all(
    const float* __restrict__ x,
    const float* __restrict__ Wa, const float* __restrict__ ba,
    const float* __restrict__ Wi, const float* __restrict__ Wh,
    const float* __restrict__ be,
    float* __restrict__ enc_out)
{
    __shared__ float act_s[8 * 320];       // 10 KB [row][0:64 ein | 64:320 h]
    __shared__ float x_s[8 * 64];          // 2 KB
    __shared__ float gate_s[2][8 * 1024];  // 64 KB two-quarter staging

    const int row0 = blockIdx.x * 8;
    const int tid  = threadIdx.x;
    const int lane = tid & 63;
    const int w    = tid >> 6;       // wave 0..15
    const int q    = tid >> 8;       // k-quarter 0..3 (wave-uniform)
    const int qq   = q & 1;          // staging slot within a phase
    const int ct   = tid & 255;      // col-quad owner
    const int c0   = ct * 4;
    const bool epi = (w < 8);        // attention + epilogue duty (== q<2)

    float4 bias4 = make_float4(0.f, 0.f, 0.f, 0.f);
    if (q == 0) bias4 = *(const float4*)&be[c0];
    const float  bav  = ba[lane];
    const float* xrow = x + (size_t)(row0 + (w & 7)) * LL * FF;
    const float* wiP  = Wi + c0;
    const float* whP  = Wh + c0;
    float c_reg[4] = {0.f, 0.f, 0.f, 0.f};

    for (int t = 0; t < LL; ++t) {
        // ---- attention: wave w (<8) -> row w, lane -> col (coalesced Wa) ----
        if (epi) {
            x_s[w * 64 + lane] = xrow[t * FF + lane];
            float a = bav;
            #pragma unroll 4
            for (int k4 = 0; k4 < 64; k4 += 4) {
                float4 xa = *(const float4*)&x_s[w * 64 + k4];
                a += xa.x * Wa[(k4 + 0) * 64 + lane]
                   + xa.y * Wa[(k4 + 1) * 64 + lane]
                   + xa.z * Wa[(k4 + 2) * 64 + lane]
                   + xa.w * Wa[(k4 + 3) * 64 + lane];
            }
            if (t > 0) {
                #pragma unroll 4
                for (int k4 = 64; k4 < 320; k4 += 4) {
                    float4 ha = *(const float4*)&act_s[w * 320 + k4];
                    a += ha.x * Wa[(k4 + 0) * 64 + lane]
                       + ha.y * Wa[(k4 + 1) * 64 + lane]
                       + ha.z * Wa[(k4 + 2) * 64 + lane]
                       + ha.w * Wa[(k4 + 3) * 64 + lane];
                }
            }
            float e = tanhf_(a);
            float m = e;
            #pragma unroll
            for (int msk = 32; msk >= 1; msk >>= 1) m = fmaxf(m, __shfl_xor(m, msk, 64));
            float ev = expf(e - m);
            float s = ev;
            #pragma unroll
            for (int msk = 32; msk >= 1; msk >>= 1) s += __shfl_xor(s, msk, 64);
            act_s[w * 320 + lane] = (ev / s) * x_s[w * 64 + lane];
        }
        __syncthreads();   // sync1: ein + prev-h visible; gate_s free to rewrite

        // ---- gates: quarter q -> chunks [q*20, q*20+20) over stacked k ----
        float4 acc[8];
        #pragma unroll
        for (int r = 0; r < 8; ++r) acc[r] = bias4;

        const int nch = (t == 0) ? (q == 0 ? 16 : 0) : 20;
        const int ch0 = q * 20;
        for (int c = 0; c < nch; ++c) {
            const int k0 = (ch0 + c) * 4;
            const float* wP = (k0 < 64) ? (wiP + (size_t)k0 * 1024)
                                        : (whP + (size_t)(k0 - 64) * 1024);
            float4 w0 = *(const float4*)&wP[0];
            float4 w1 = *(const float4*)&wP[1024];
            float4 w2 = *(const float4*)&wP[2048];
            float4 w3 = *(const float4*)&wP[3072];
            #pragma unroll
            for (int r = 0; r < 8; ++r) {
                float4 av = *(const float4*)&act_s[r * 320 + k0];
                acc[r].x += av.x * w0.x; acc[r].y += av.x * w0.y;
                acc[r].z += av.x * w0.z; acc[r].w += av.x * w0.w;
                acc[r].x += av.y * w1.x; acc[r].y += av.y * w1.y;
                acc[r].z += av.y * w1.z; acc[r].w += av.y * w1.w;
                acc[r].x += av.z * w2.x; acc[r].y += av.z * w2.y;
                acc[r].z += av.z * w2.z; acc[r].w += av.z * w2.w;
                acc[r].x += av.w * w3.x; acc[r].y += av.w * w3.y;
                acc[r].z += av.w * w3.z; acc[r].w += av.w * w3.w;
            }
        }
        // phase 1: quarters 0,1 stage
        if (q < 2) {
            #pragma unroll
            for (int r = 0; r < 8; ++r)
                *(float4*)&gate_s[qq][r * 1024 + c0] = acc[r];
        }
        __syncthreads();   // sync2: phase-1 staged

        float part[16];
        if (epi) {
            #pragma unroll
            for (int g = 0; g < 4; ++g) {
                float4 a4 = *(const float4*)&gate_s[0][w * 1024 + g * 256 + lane * 4];
                float4 b4 = *(const float4*)&gate_s[1][w * 1024 + g * 256 + lane * 4];
                part[g * 4 + 0] = a4.x + b4.x;
                part[g * 4 + 1] = a4.y + b4.y;
                part[g * 4 + 2] = a4.z + b4.z;
                part[g * 4 + 3] = a4.w + b4.w;
            }
        }
        __syncthreads();   // sync3: phase-1 consumed

        // phase 2: quarters 2,3 stage
        if (q >= 2) {
            #pragma unroll
            for (int r = 0; r < 8; ++r)
                *(float4*)&gate_s[qq][r * 1024 + c0] = acc[r];
        }
        __syncthreads();   // sync4: phase-2 staged

        // ---- epilogue: wave-local. lane -> units lane*4..+3 of row w ----
        if (epi) {
            #pragma unroll
            for (int g = 0; g < 4; ++g) {
                float4 a4 = *(const float4*)&gate_s[0][w * 1024 + g * 256 + lane * 4];
                float4 b4 = *(const float4*)&gate_s[1][w * 1024 + g * 256 + lane * 4];
                part[g * 4 + 0] += a4.x + b4.x;
                part[g * 4 + 1] += a4.y + b4.y;
                part[g * 4 + 2] += a4.z + b4.z;
                part[g * 4 + 3] += a4.w + b4.w;
            }
            float4 hn;
            #pragma unroll
            for (int uu = 0; uu < 4; ++uu) {
                float gi = part[0 + uu], gf = part[4 + uu];
                float gg = part[8 + uu], go = part[12 + uu];
                float cn = sigmoidf_(gf) * c_reg[uu] + sigmoidf_(gi) * tanhf_(gg);
                c_reg[uu] = cn;
                float hv = sigmoidf_(go) * tanhf_(cn);
                if (uu == 0) hn.x = hv; else if (uu == 1) hn.y = hv;
                else if (uu == 2) hn.z = hv; else hn.w = hv;
            }
            *(float4*)&act_s[w * 320 + 64 + lane * 4] = hn;
            *(float4*)&enc_out[((size_t)t * BB + row0 + w) * 256 + lane * 4] = hn;
        }
        // next-iter sync1 guards cross-wave act_s reads and gate_s reuse.
    }
}

// ---------------------------------------------------------------------------
// Generic fp32 GEMM C(M,256) = A(M,256) @ W(256,256) [+ bias].
// Block = 32 rows, 256 threads: rg = tid>>6 owns 8 rows, lane owns 4 cols.
// A tile staged in LDS (wave-uniform broadcast reads, conflict-free);
// W read as lane-contiguous float4 (1KB/wave-inst, L1-amplified across rgs).
// skip_gemm: C = bias broadcast (decoder step 0 where hd == 0).
// Used for: enc_part = enc_out @ Wd_top (once)  and  hp = hd @ Wd_bot + bd.
// ---------------------------------------------------------------------------
__global__ __launch_bounds__(256) void gemm_nk256(
    const float* __restrict__ A, const float* __restrict__ W,
    const float* __restrict__ bias, float* __restrict__ C, int skip_gemm)
{
    __shared__ float a_s[32 * 256];   // 32 KB
    const int m0   = blockIdx.x * 32;
    const int tid  = threadIdx.x;
    const int lane = tid & 63;
    const int rg   = tid >> 6;        // 0..3 -> rows rg*8..rg*8+7
    const int n0   = lane * 4;

    float4 bias4 = make_float4(0.f, 0.f, 0.f, 0.f);
    if (bias) bias4 = *(const float4*)&bias[n0];

    if (skip_gemm) {
        #pragma unroll
        for (int r = 0; r < 8; ++r)
            *(float4*)&C[(size_t)(m0 + rg * 8 + r) * 256 + n0] = bias4;
        return;
    }

    for (int v = tid; v < 32 * 64; v += 256)
        ((float4*)a_s)[v] = ((const float4*)(A + (size_t)m0 * 256))[v];
    __syncthreads();

    float4 acc[8];
    #pragma unroll
    for (int r = 0; r < 8; ++r) acc[r] = bias4;

    #pragma unroll 2
    for (int k = 0; k < 256; k += 4) {
        float4 wv[4];
        #pragma unroll
        for (int kk = 0; kk < 4; ++kk)
            wv[kk] = *(const float4*)&W[(size_t)(k + kk) * 256 + n0];
        float4 av[8];
        #pragma unroll
        for (int r = 0; r < 8; ++r)
            av[r] = *(const float4*)&a_s[(rg * 8 + r) * 256 + k];
        #pragma unroll
        for (int kk = 0; kk < 4; ++kk) {
            #pragma unroll
            for (int r = 0; r < 8; ++r) {
                float e = COMP(av[r], kk);
                acc[r].x += e * wv[kk].x; acc[r].y += e * wv[kk].y;
                acc[r].z += e * wv[kk].z; acc[r].w += e * wv[kk].w;
            }
        }
    }
    #pragma unroll
    for (int r = 0; r < 8; ++r)
        *(float4*)&C[(size_t)(m0 + rg * 8 + r) * 256 + n0] = acc[r];
}

// ---------------------------------------------------------------------------
// Per-step decoder scores from the precomputed enc_part:
//   score[l,b] = Wl . tanh(enc_part[l,b,:] + hp[b,:])
// (bl dropped: constant over l, cancels in the softmax.)
// Grid (B/8, L/20), 256 threads: thread -> (row r = tid>>5, group g = tid&31);
// each thread covers elems g*4..+3 and 128+g*4..+3; 32-lane shuffle reduce.
// Memory-bound: streams enc_part once (210 MB total across grid).
// ---------------------------------------------------------------------------
__global__ __launch_bounds__(256) void scores_ep(
    const float* __restrict__ ep, const float* __restrict__ hp,
    const float* __restrict__ Wl, float* __restrict__ scores)
{
    __shared__ float hp_s[8 * 256];
    const int b0  = blockIdx.x * 8;
    const int l0  = blockIdx.y * 20;
    const int tid = threadIdx.x;
    const int r   = tid >> 5;    // 0..7
    const int g   = tid & 31;

    for (int v = tid; v < 512; v += 256)
        ((float4*)hp_s)[v] = ((const float4*)(hp + (size_t)b0 * 256))[v];
    __syncthreads();

    const float4 wl0 = *(const float4*)&Wl[g * 4];
    const float4 wl1 = *(const float4*)&Wl[128 + g * 4];
    const float4 h0  = *(const float4*)&hp_s[r * 256 + g * 4];
    const float4 h1  = *(const float4*)&hp_s[r * 256 + 128 + g * 4];
    const float* eb  = ep + (size_t)l0 * (BB * 256) + (size_t)(b0 + r) * 256;

    #pragma unroll 2
    for (int li = 0; li < 20; ++li) {
        float4 e0 = *(const float4*)&eb[(size_t)li * (BB * 256) + g * 4];
        float4 e1 = *(const float4*)&eb[(size_t)li * (BB * 256) + 128 + g * 4];
        float p = tanhf_(e0.x + h0.x) * wl0.x + tanhf_(e0.y + h0.y) * wl0.y
                + tanhf_(e0.z + h0.z) * wl0.z + tanhf_(e0.w + h0.w) * wl0.w
                + tanhf_(e1.x + h1.x) * wl1.x + tanhf_(e1.y + h1.y) * wl1.y
                + tanhf_(e1.z + h1.z) * wl1.z + tanhf_(e1.w + h1.w) * wl1.w;
        #pragma unroll
        for (int msk = 16; msk >= 1; msk >>= 1) p += __shfl_xor(p, msk, 64);
        if (g == 0) scores[(size_t)(l0 + li) * BB + b0 + r] = p;
    }
}

// ---------------------------------------------------------------------------
// Fused decoder attention scores, Lin=2. grid (B/16, 5), 256 threads.
// (fallback path when workspace can't hold enc_part)
// ---------------------------------------------------------------------------
#define SC_LIN 2
__global__ __launch_bounds__(256) void scores_fused(
    const float* __restrict__ enc_out, const float* __restrict__ Wd,
    const float* __restrict__ bd,
    const float* __restrict__ Wl, const float* __restrict__ bl,
    const float* __restrict__ hd, float* __restrict__ scores, int first)
{
    __shared__ float enc_s[SC_LIN * 16 * 256];   // 32 KB
    const int b0   = blockIdx.x * 16;
    const int l0   = blockIdx.y * 20;
    const int tid  = threadIdx.x;
    const int lane = tid & 63;
    const int rg   = tid >> 6;
    const int n0   = lane * 4;

    float hdp[4][4];
    {
        float4 bd4 = *(const float4*)&bd[n0];
        #pragma unroll
        for (int r = 0; r < 4; ++r) {
            hdp[r][0] = bd4.x; hdp[r][1] = bd4.y; hdp[r][2] = bd4.z; hdp[r][3] = bd4.w;
        }
    }
    if (!first) {
        for (int v = tid; v < 1024; v += 256) {
            int r = v >> 6, qq = v & 63;
            *(float4*)&enc_s[r * 256 + qq * 4] =
                *(const float4*)(hd + (size_t)(b0 + r) * 256 + qq * 4);
        }
        __syncthreads();
        const float* wb = Wd + 256 * 256;
        #pragma unroll 2
        for (int k = 0; k < 256; k += 4) {
            float4 hv[4];
            #pragma unroll
            for (int r = 0; r < 4; ++r) hv[r] = *(const float4*)&enc_s[(rg * 4 + r) * 256 + k];
            #pragma unroll
            for (int kk = 0; kk < 4; ++kk) {
                float4 wv = *(const float4*)&wb[(size_t)(k + kk) * 256 + n0];
                #pragma unroll
                for (int r = 0; r < 4; ++r) {
                    float e = COMP(hv[r], kk);
                    hdp[r][0] += e * wv.x; hdp[r][1] += e * wv.y;
                    hdp[r][2] += e * wv.z; hdp[r][3] += e * wv.w;
                }
            }
        }
        __syncthreads();
    }
    float4 wl4 = *(const float4*)&Wl[n0];
    const float blv = bl[0];

    for (int lo = 0; lo < 20; lo += SC_LIN) {
        for (int v = tid; v < SC_LIN * 16 * 64; v += 256) {
            int li = v >> 10, rem = v & 1023;
            int r = rem >> 6, qq = rem & 63;
            *(float4*)&enc_s[li * 4096 + r * 256 + qq * 4] =
                *(const float4*)(enc_out + (size_t)(l0 + lo + li) * (BB * 256)
                                 + (size_t)(b0 + r) * 256 + qq * 4);
        }
        __syncthreads();

        float acc[SC_LIN][4][4];
        #pragma unroll
        for (int li = 0; li < SC_LIN; ++li)
            #pragma unroll
            for (int r = 0; r < 4; ++r)
                #pragma unroll
                for (int c = 0; c < 4; ++c) acc[li][r][c] = hdp[r][c];

        for (int k = 0; k < 256; k += 4) {
            float4 wv[4];
            #pragma unroll
            for (int kk = 0; kk < 4; ++kk)
                wv[kk] = *(const float4*)&Wd[(size_t)(k + kk) * 256 + n0];
            #pragma unroll
            for (int li = 0; li < SC_LIN; ++li) {
                float4 ev[4];
                #pragma unroll
                for (int r = 0; r < 4; ++r)
                    ev[r] = *(const float4*)&enc_s[li * 4096 + (rg * 4 + r) * 256 + k];
                #pragma unroll
                for (int kk = 0; kk < 4; ++kk) {
                    #pragma unroll
                    for (int r = 0; r < 4; ++r) {
                        float e = COMP(ev[r], kk);
                        acc[li][r][0] += e * wv[kk].x; acc[li][r][1] += e * wv[kk].y;
                        acc[li][r][2] += e * wv[kk].z; acc[li][r][3] += e * wv[kk].w;
                    }
                }
            }
        }
        #pragma unroll
        for (int li = 0; li < SC_LIN; ++li) {
            #pragma unroll
            for (int r = 0; r < 4; ++r) {
                float p = tanhf_(acc[li][r][0]) * wl4.x + tanhf_(acc[li][r][1]) * wl4.y
                        + tanhf_(acc[li][r][2]) * wl4.z + tanhf_(acc[li][r][3]) * wl4.w;
                #pragma unroll
                for (int msk = 32; msk >= 1; msk >>= 1) p += __shfl_xor(p, msk, 64);
                if (lane == 0)
                    scores[(size_t)(l0 + lo + li) * BB + b0 + rg * 4 + r] = p + blv;
            }
        }
        __syncthreads();
    }
}

// ---------------------------------------------------------------------------
// softmax over L + ctx from scores buffer. Block = 8 rows.
// ---------------------------------------------------------------------------
__global__ __launch_bounds__(256) void softmax_ctx(
    const float* __restrict__ scores, const float* __restrict__ enc_out,
    float* __restrict__ ctx)
{
    __shared__ float al_s[8 * 100];
    const int b0  = blockIdx.x * 8;
    const int tid = threadIdx.x;
    for (int v = tid; v < 800; v += 256) {
        int r = v / 100, l = v - r * 100;
        al_s[r * 100 + l] = scores[(size_t)l * BB + b0 + r];
    }
    __syncthreads();
    if (tid < 8) {
        float m = -1e30f;
        for (int l = 0; l < LL; ++l) m = fmaxf(m, al_s[tid * 100 + l]);
        float s = 0.f;
        for (int l = 0; l < LL; ++l) { float e = expf(al_s[tid * 100 + l] - m); al_s[tid * 100 + l] = e; s += e; }
        float inv = 1.f / s;
        for (int l = 0; l < LL; ++l) al_s[tid * 100 + l] *= inv;
    }
    __syncthreads();
    float acc[8] = {};
    for (int l = 0; l < LL; ++l) {
        const float* er = enc_out + (size_t)l * (BB * 256) + (size_t)b0 * 256 + tid;
        #pragma unroll
        for (int r = 0; r < 8; ++r) acc[r] += al_s[r * 100 + l] * er[r * 256];
    }
    for (int r = 0; r < 8; ++r) ctx[(size_t)(b0 + r) * 256 + tid] = acc[r];
}

// ---------------------------------------------------------------------------
// Decoder LSTM cell: grid 256 x 512, block = 8 rows, half0 = ctx@Wdi,
// half1 = hd@Wdh, coalesced float4 weights. hd updated in place.
// ---------------------------------------------------------------------------
__global__ __launch_bounds__(512) void dec_step(
    const float* __restrict__ ctxp,
    const float* __restrict__ Wdi, const float* __restrict__ Wdh,
    const float* __restrict__ bdec,
    float* __restrict__ hd, float* __restrict__ c_st, int first)
{
    __shared__ float ct_s[8 * 256];        // 8 KB
    __shared__ float hd_s[8 * 256];        // 8 KB
    __shared__ float gate_s[2][8 * 1024];  // 64 KB
    const int row0 = blockIdx.x * 8;
    const int tid  = threadIdx.x;
    const int lane = tid & 63, w = tid >> 6;
    const int half = tid >> 8;
    const int ct   = tid & 255;
    const int c0   = ct * 4;

    ((float4*)ct_s)[tid] = ((const float4*)(ctxp + (size_t)row0 * 256))[tid];
    if (!first)
        ((float4*)hd_s)[tid] = ((const float4*)(hd + (size_t)row0 * 256))[tid];
    __syncthreads();

    float4 acc[8];
    {
        float4 b4 = *(const float4*)&bdec[c0];
        float4 bias4 = (half == 0) ? b4 : make_float4(0.f, 0.f, 0.f, 0.f);
        #pragma unroll
        for (int r = 0; r < 8; ++r) acc[r] = bias4;
    }
    if (half == 0) {
        const float* wP = Wdi + c0;
        #pragma unroll 2
        for (int ch = 0; ch < 64; ++ch) {
            const int k0 = ch * 4;
            float4 w0 = *(const float4*)&wP[(size_t)(k0 + 0) * 1024];
            float4 w1 = *(const float4*)&wP[(size_t)(k0 + 1) * 1024];
            float4 w2 = *(const float4*)&wP[(size_t)(k0 + 2) * 1024];
            float4 w3 = *(const float4*)&wP[(size_t)(k0 + 3) * 1024];
            #pragma unroll
            for (int r = 0; r < 8; ++r) {
                float4 av = *(const float4*)&ct_s[r * 256 + k0];
                acc[r].x += av.x * w0.x; acc[r].y += av.x * w0.y;
                acc[r].z += av.x * w0.z; acc[r].w += av.x * w0.w;
                acc[r].x += av.y * w1.x; acc[r].y += av.y * w1.y;
                acc[r].z += av.y * w1.z; acc[r].w += av.y * w1.w;
                acc[r].x += av.z * w2.x; acc[r].y += av.z * w2.y;
                acc[r].z += av.z * w2.z; acc[r].w += av.z * w2.w;
                acc[r].x += av.w * w3.x; acc[r].y += av.w * w3.y;
                acc[r].z += av.w * w3.z; acc[r].w += av.w * w3.w;
            }
        }
    } else if (!first) {
        const float* wP = Wdh + c0;
        #pragma unroll 2
        for (int ch = 0; ch < 64; ++ch) {
            const int k0 = ch * 4;
            float4 w0 = *(const float4*)&wP[(size_t)(k0 + 0) * 1024];
            float4 w1 = *(const float4*)&wP[(size_t)(k0 + 1) * 1024];
            float4 w2 = *(const float4*)&wP[(size_t)(k0 + 2) * 1024];
            float4 w3 = *(const float4*)&wP[(size_t)(k0 + 3) * 1024];
            #pragma unroll
            for (int r = 0; r < 8; ++r) {
                float4 av = *(const float4*)&hd_s[r * 256 + k0];
                acc[r].x += av.x * w0.x; acc[r].y += av.x * w0.y;
                acc[r].z += av.x * w0.z; acc[r].w += av.x * w0.w;
                acc[r].x += av.y * w1.x; acc[r].y += av.y * w1.y;
                acc[r].z += av.y * w1.z; acc[r].w += av.y * w1.w;
                acc[r].x += av.z * w2.x; acc[r].y += av.z * w2.y;
                acc[r].z += av.z * w2.z; acc[r].w += av.z * w2.w;
                acc[r].x += av.w * w3.x; acc[r].y += av.w * w3.y;
                acc[r].z += av.w * w3.z; acc[r].w += av.w * w3.w;
            }
        }
    }
    #pragma unroll
    for (int r = 0; r < 8; ++r)
        *(float4*)&gate_s[half][r * 1024 + c0] = acc[r];
    __syncthreads();

    // epilogue: wave-local row w, lane -> 4 units
    {
        const float* g0 = &gate_s[0][w * 1024 + lane * 4];
        const float* g1 = &gate_s[1][w * 1024 + lane * 4];
        float4 giA = *(const float4*)&g0[0],   giB = *(const float4*)&g1[0];
        float4 gfA = *(const float4*)&g0[256], gfB = *(const float4*)&g1[256];
        float4 ggA = *(const float4*)&g0[512], ggB = *(const float4*)&g1[512];
        float4 goA = *(const float4*)&g0[768], goB = *(const float4*)&g1[768];
        size_t ci = (size_t)(row0 + w) * 256 + lane * 4;
        float4 c4 = first ? make_float4(0.f, 0.f, 0.f, 0.f)
                          : *(const float4*)&c_st[ci];
        float cc[4] = { c4.x, c4.y, c4.z, c4.w };
        float gi[4] = { giA.x + giB.x, giA.y + giB.y, giA.z + giB.z, giA.w + giB.w };
        float gf[4] = { gfA.x + gfB.x, gfA.y + gfB.y, gfA.z + gfB.z, gfA.w + gfB.w };
        float gg[4] = { ggA.x + ggB.x, ggA.y + ggB.y, ggA.z + ggB.z, ggA.w + ggB.w };
        float go[4] = { goA.x + goB.x, goA.y + goB.y, goA.z + goB.z, goA.w + goB.w };
        float4 cn, hn;
        #pragma unroll
        for (int uu = 0; uu < 4; ++uu) {
            float cv = sigmoidf_(gf[uu]) * cc[uu] + sigmoidf_(gi[uu]) * tanhf_(gg[uu]);
            float hv = sigmoidf_(go[uu]) * tanhf_(cv);
            if (uu == 0) { cn.x = cv; hn.x = hv; } else if (uu == 1) { cn.y = cv; hn.y = hv; }
            else if (uu == 2) { cn.z = cv; hn.z = hv; } else { cn.w = cv; hn.w = hv; }
        }
        *(float4*)&c_st[ci] = cn;
        *(float4*)&hd[ci]   = hn;
    }
}

// ---------------------------------------------------------------------------
// Head: fc = tanh(h_d@Wf+bf); out[:,step] = tanh(fc@Wo+bo). Block = 16 rows.
// ---------------------------------------------------------------------------
__global__ __launch_bounds__(256) void head_k(
    const float* __restrict__ hd, const float* __restrict__ Wf,
    const float* __restrict__ bf, const float* __restrict__ Wo,
    const float* __restrict__ bo, float* __restrict__ out, int step)
{
    __shared__ float hd_s[16 * 256];
    __shared__ float fc_s[16 * 128];
    const int b0  = blockIdx.x * 16;
    const int tid = threadIdx.x;
    {
        const float4* hg = (const float4*)(hd + (size_t)b0 * 256);
        for (int i = tid; i < 1024; i += 256) ((float4*)hd_s)[i] = hg[i];
    }
    __syncthreads();
    {
        const int f = tid & 127, rg = tid >> 7;
        float acc[8];
        float bfv = bf[f];
        #pragma unroll
        for (int rr = 0; rr < 8; ++rr) acc[rr] = bfv;
        const float* wp = Wf + f;
        #pragma unroll 2
        for (int k = 0; k < 256; ++k) {
            float wv = wp[k * 128];
            #pragma unroll
            for (int rr = 0; rr < 8; ++rr) acc[rr] += hd_s[(rg * 8 + rr) * 256 + k] * wv;
        }
        for (int rr = 0; rr < 8; ++rr) fc_s[(rg * 8 + rr) * 128 + f] = tanhf_(acc[rr]);
    }
    __syncthreads();
    {
        const int lane = tid & 63, w = tid >> 6;
        const float bov = bo[0];
        #pragma unroll
        for (int rr = 0; rr < 4; ++rr) {
            int r = w * 4 + rr;
            float p = fc_s[r * 128 + lane] * Wo[lane] + fc_s[r * 128 + 64 + lane] * Wo[64 + lane];
            #pragma unroll
            for (int msk = 32; msk >= 1; msk >>= 1) p += __shfl_xor(p, msk, 64);
            if (lane == 0) out[(size_t)(b0 + r) * NOUT + step] = tanhf_(p + bov);
        }
    }
}

extern "C" void kernel_launch(void* const* d_in, const int* in_sizes, int n_in,
                              void* d_out, int out_size, void* d_ws, size_t ws_size,
                              hipStream_t stream)
{
    const float* x    = (const float*)d_in[0];
    const float* Wa   = (const float*)d_in[1];
    const float* ba   = (const float*)d_in[2];
    const float* Wi   = (const float*)d_in[3];
    const float* Wh   = (const float*)d_in[4];
    const float* be   = (const float*)d_in[5];
    const float* Wd   = (const float*)d_in[6];
    const float* bd   = (const float*)d_in[7];
    const float* Wl   = (const float*)d_in[8];
    const float* bl   = (const float*)d_in[9];
    const float* Wdi  = (const float*)d_in[10];
    const float* Wdh  = (const float*)d_in[11];
    const float* bdec = (const float*)d_in[12];
    const float* Wf   = (const float*)d_in[13];
    const float* bf   = (const float*)d_in[14];
    const float* Wo   = (const float*)d_in[15];
    const float* bo   = (const float*)d_in[16];
    float* out = (float*)d_out;

    // ws layout (floats): enc_out | hd | c_d | ctx | scores | [enc_part | hp]
    const size_t f_enc    = (size_t)LL * BB * EE;     // 52,428,800
    const size_t f_state  = (size_t)BB * EE;          // 524,288
    const size_t f_scores = (size_t)LL * BB;          // 204,800
    const size_t need_base = f_enc + 3 * f_state + f_scores;            // ~216.8 MB
    const size_t need_big  = need_base + f_enc + f_state;               // ~428.4 MB

    float* ws       = (float*)d_ws;
    float* enc_out  = ws;
    float* hd       = enc_out + f_enc;
    float* c_d      = hd + f_state;
    float* ctx      = c_d + f_state;
    float* scores   = ctx + f_state;
    float* enc_part = scores + f_scores;
    float* hp       = enc_part + f_enc;

    if (ws_size < need_base * sizeof(float)) return;   // diagnostic clean-fail
    const bool big = (ws_size >= need_big * sizeof(float));

    // persistent encoder: one dispatch, 1024-thread blocks (4 waves/SIMD)
    enc_all<<<BB / 8, 1024, 0, stream>>>(x, Wa, ba, Wi, Wh, be, enc_out);

    if (big) {
        // hoist the step-invariant enc_out @ Wd_top out of the decode loop
        gemm_nk256<<<(LL * BB) / 32, 256, 0, stream>>>(
            enc_out, Wd, (const float*)nullptr, enc_part, 0);
    }

    for (int s = 0; s < NOUT; ++s) {
        if (big) {
            // hp = hd @ Wd_bot + bd  (step 0: hd == 0 -> hp = bd)
            gemm_nk256<<<BB / 32, 256, 0, stream>>>(
                hd, Wd + 256 * 256, bd, hp, s == 0);
            scores_ep<<<dim3(BB / 8, 5), 256, 0, stream>>>(
                enc_part, hp, Wl, scores);
        } else {
            scores_fused<<<dim3(BB / 16, 5), 256, 0, stream>>>(
                enc_out, Wd, bd, Wl, bl, hd, scores, s == 0);
        }
        softmax_ctx<<<BB / 8, 256, 0, stream>>>(scores, enc_out, ctx);
        dec_step<<<BB / 8, 512, 0, stream>>>(ctx, Wdi, Wdh, bdec, hd, c_d, s == 0);
        head_k<<<BB / 16, 256, 0, stream>>>(hd, Wf, bf, Wo, bo, out, s);
    }
}

// Round 2
// 3760.887 us; speedup vs baseline: 1.1810x; 1.1810x over previous
//
#include <hip/hip_runtime.h>
#include <math.h>

// Problem constants
#define BB 2048
#define LL 100
#define FF 64
#define EE 256
#define DD 256
#define NOUT 3

#define COMP(v, i) ((i) == 0 ? (v).x : (i) == 1 ? (v).y : (i) == 2 ? (v).z : (v).w)

typedef unsigned short u16;
typedef unsigned int u32;

__device__ __forceinline__ float sigmoidf_(float x) {
    return 1.0f / (1.0f + expf(-x));
}
// tanh via identity 1 - 2/(1+e^{2x}); ~2e-7 abs fp32 error, saturates correctly.
__device__ __forceinline__ float tanhf_(float x) {
    return 1.0f - 2.0f / (1.0f + expf(2.0f * x));
}
// fp32 -> bf16 round-to-nearest-even
__device__ __forceinline__ u16 f2b_(float f) {
    u32 u = __float_as_uint(f);
    u = (u + 0x7FFFu + ((u >> 16) & 1u)) >> 16;
    return (u16)u;
}
__device__ __forceinline__ float b2f_(u16 b) {
    return __uint_as_float(((u32)b) << 16);
}
__device__ __forceinline__ u32 pack2_(float a, float b) {
    return (u32)f2b_(a) | ((u32)f2b_(b) << 16);
}

// ---------------------------------------------------------------------------
// Persistent encoder, 1024-thread blocks (16 waves -> 4 waves/SIMD at 1
// block/CU) with 4-way k-split. grid 256; block owns 8 rows for all 100 steps.
// (unchanged from previous round -- VALU-bound at ~65% busy)
// ---------------------------------------------------------------------------
__global__ __launch_bounds__(1024) void enc_all(
    const float* __restrict__ x,
    const float* __restrict__ Wa, const float* __restrict__ ba,
    const float* __restrict__ Wi, const float* __restrict__ Wh,
    const float* __restrict__ be,
    float* __restrict__ enc_out)
{
    __shared__ float act_s[8 * 320];       // 10 KB [row][0:64 ein | 64:320 h]
    __shared__ float x_s[8 * 64];          // 2 KB
    __shared__ float gate_s[2][8 * 1024];  // 64 KB two-quarter staging

    const int row0 = blockIdx.x * 8;
    const int tid  = threadIdx.x;
    const int lane = tid & 63;
    const int w    = tid >> 6;       // wave 0..15
    const int q    = tid >> 8;       // k-quarter 0..3 (wave-uniform)
    const int qq   = q & 1;          // staging slot within a phase
    const int ct   = tid & 255;      // col-quad owner
    const int c0   = ct * 4;
    const bool epi = (w < 8);        // attention + epilogue duty (== q<2)

    float4 bias4 = make_float4(0.f, 0.f, 0.f, 0.f);
    if (q == 0) bias4 = *(const float4*)&be[c0];
    const float  bav  = ba[lane];
    const float* xrow = x + (size_t)(row0 + (w & 7)) * LL * FF;
    const float* wiP  = Wi + c0;
    const float* whP  = Wh + c0;
    float c_reg[4] = {0.f, 0.f, 0.f, 0.f};

    for (int t = 0; t < LL; ++t) {
        // ---- attention: wave w (<8) -> row w, lane -> col (coalesced Wa) ----
        if (epi) {
            x_s[w * 64 + lane] = xrow[t * FF + lane];
            float a = bav;
            #pragma unroll 4
            for (int k4 = 0; k4 < 64; k4 += 4) {
                float4 xa = *(const float4*)&x_s[w * 64 + k4];
                a += xa.x * Wa[(k4 + 0) * 64 + lane]
                   + xa.y * Wa[(k4 + 1) * 64 + lane]
                   + xa.z * Wa[(k4 + 2) * 64 + lane]
                   + xa.w * Wa[(k4 + 3) * 64 + lane];
            }
            if (t > 0) {
                #pragma unroll 4
                for (int k4 = 64; k4 < 320; k4 += 4) {
                    float4 ha = *(const float4*)&act_s[w * 320 + k4];
                    a += ha.x * Wa[(k4 + 0) * 64 + lane]
                       + ha.y * Wa[(k4 + 1) * 64 + lane]
                       + ha.z * Wa[(k4 + 2) * 64 + lane]
                       + ha.w * Wa[(k4 + 3) * 64 + lane];
                }
            }
            float e = tanhf_(a);
            float m = e;
            #pragma unroll
            for (int msk = 32; msk >= 1; msk >>= 1) m = fmaxf(m, __shfl_xor(m, msk, 64));
            float ev = expf(e - m);
            float s = ev;
            #pragma unroll
            for (int msk = 32; msk >= 1; msk >>= 1) s += __shfl_xor(s, msk, 64);
            act_s[w * 320 + lane] = (ev / s) * x_s[w * 64 + lane];
        }
        __syncthreads();   // sync1: ein + prev-h visible; gate_s free to rewrite

        // ---- gates: quarter q -> chunks [q*20, q*20+20) over stacked k ----
        float4 acc[8];
        #pragma unroll
        for (int r = 0; r < 8; ++r) acc[r] = bias4;

        const int nch = (t == 0) ? (q == 0 ? 16 : 0) : 20;
        const int ch0 = q * 20;
        for (int c = 0; c < nch; ++c) {
            const int k0 = (ch0 + c) * 4;
            const float* wP = (k0 < 64) ? (wiP + (size_t)k0 * 1024)
                                        : (whP + (size_t)(k0 - 64) * 1024);
            float4 w0 = *(const float4*)&wP[0];
            float4 w1 = *(const float4*)&wP[1024];
            float4 w2 = *(const float4*)&wP[2048];
            float4 w3 = *(const float4*)&wP[3072];
            #pragma unroll
            for (int r = 0; r < 8; ++r) {
                float4 av = *(const float4*)&act_s[r * 320 + k0];
                acc[r].x += av.x * w0.x; acc[r].y += av.x * w0.y;
                acc[r].z += av.x * w0.z; acc[r].w += av.x * w0.w;
                acc[r].x += av.y * w1.x; acc[r].y += av.y * w1.y;
                acc[r].z += av.y * w1.z; acc[r].w += av.y * w1.w;
                acc[r].x += av.z * w2.x; acc[r].y += av.z * w2.y;
                acc[r].z += av.z * w2.z; acc[r].w += av.z * w2.w;
                acc[r].x += av.w * w3.x; acc[r].y += av.w * w3.y;
                acc[r].z += av.w * w3.z; acc[r].w += av.w * w3.w;
            }
        }
        // phase 1: quarters 0,1 stage
        if (q < 2) {
            #pragma unroll
            for (int r = 0; r < 8; ++r)
                *(float4*)&gate_s[qq][r * 1024 + c0] = acc[r];
        }
        __syncthreads();   // sync2: phase-1 staged

        float part[16];
        if (epi) {
            #pragma unroll
            for (int g = 0; g < 4; ++g) {
                float4 a4 = *(const float4*)&gate_s[0][w * 1024 + g * 256 + lane * 4];
                float4 b4 = *(const float4*)&gate_s[1][w * 1024 + g * 256 + lane * 4];
                part[g * 4 + 0] = a4.x + b4.x;
                part[g * 4 + 1] = a4.y + b4.y;
                part[g * 4 + 2] = a4.z + b4.z;
                part[g * 4 + 3] = a4.w + b4.w;
            }
        }
        __syncthreads();   // sync3: phase-1 consumed

        // phase 2: quarters 2,3 stage
        if (q >= 2) {
            #pragma unroll
            for (int r = 0; r < 8; ++r)
                *(float4*)&gate_s[qq][r * 1024 + c0] = acc[r];
        }
        __syncthreads();   // sync4: phase-2 staged

        // ---- epilogue: wave-local. lane -> units lane*4..+3 of row w ----
        if (epi) {
            #pragma unroll
            for (int g = 0; g < 4; ++g) {
                float4 a4 = *(const float4*)&gate_s[0][w * 1024 + g * 256 + lane * 4];
                float4 b4 = *(const float4*)&gate_s[1][w * 1024 + g * 256 + lane * 4];
                part[g * 4 + 0] += a4.x + b4.x;
                part[g * 4 + 1] += a4.y + b4.y;
                part[g * 4 + 2] += a4.z + b4.z;
                part[g * 4 + 3] += a4.w + b4.w;
            }
            float4 hn;
            #pragma unroll
            for (int uu = 0; uu < 4; ++uu) {
                float gi = part[0 + uu], gf = part[4 + uu];
                float gg = part[8 + uu], go = part[12 + uu];
                float cn = sigmoidf_(gf) * c_reg[uu] + sigmoidf_(gi) * tanhf_(gg);
                c_reg[uu] = cn;
                float hv = sigmoidf_(go) * tanhf_(cn);
                if (uu == 0) hn.x = hv; else if (uu == 1) hn.y = hv;
                else if (uu == 2) hn.z = hv; else hn.w = hv;
            }
            *(float4*)&act_s[w * 320 + 64 + lane * 4] = hn;
            *(float4*)&enc_out[((size_t)t * BB + row0 + w) * 256 + lane * 4] = hn;
        }
        // next-iter sync1 guards cross-wave act_s reads and gate_s reuse.
    }
}

// ---------------------------------------------------------------------------
// Generic fp32 GEMM C(M,256) = A(M,256) @ W(256,256) [+ bias].
// Block = 32 rows, 256 threads. skip_gemm: C = bias (decoder step 0, hd==0).
// Used for: hp = hd @ Wd_bot + bd   and (tier1) ep32 = enc_out @ Wd_top.
// ---------------------------------------------------------------------------
__global__ __launch_bounds__(256) void gemm_nk256(
    const float* __restrict__ A, const float* __restrict__ W,
    const float* __restrict__ bias, float* __restrict__ C, int skip_gemm)
{
    __shared__ float a_s[32 * 256];   // 32 KB
    const int m0   = blockIdx.x * 32;
    const int tid  = threadIdx.x;
    const int lane = tid & 63;
    const int rg   = tid >> 6;        // 0..3 -> rows rg*8..rg*8+7
    const int n0   = lane * 4;

    float4 bias4 = make_float4(0.f, 0.f, 0.f, 0.f);
    if (bias) bias4 = *(const float4*)&bias[n0];

    if (skip_gemm) {
        #pragma unroll
        for (int r = 0; r < 8; ++r)
            *(float4*)&C[(size_t)(m0 + rg * 8 + r) * 256 + n0] = bias4;
        return;
    }

    for (int v = tid; v < 32 * 64; v += 256)
        ((float4*)a_s)[v] = ((const float4*)(A + (size_t)m0 * 256))[v];
    __syncthreads();

    float4 acc[8];
    #pragma unroll
    for (int r = 0; r < 8; ++r) acc[r] = bias4;

    #pragma unroll 2
    for (int k = 0; k < 256; k += 4) {
        float4 wv[4];
        #pragma unroll
        for (int kk = 0; kk < 4; ++kk)
            wv[kk] = *(const float4*)&W[(size_t)(k + kk) * 256 + n0];
        float4 av[8];
        #pragma unroll
        for (int r = 0; r < 8; ++r)
            av[r] = *(const float4*)&a_s[(rg * 8 + r) * 256 + k];
        #pragma unroll
        for (int kk = 0; kk < 4; ++kk) {
            #pragma unroll
            for (int r = 0; r < 8; ++r) {
                float e = COMP(av[r], kk);
                acc[r].x += e * wv[kk].x; acc[r].y += e * wv[kk].y;
                acc[r].z += e * wv[kk].z; acc[r].w += e * wv[kk].w;
            }
        }
    }
    #pragma unroll
    for (int r = 0; r < 8; ++r)
        *(float4*)&C[(size_t)(m0 + rg * 8 + r) * 256 + n0] = acc[r];
}

// ---------------------------------------------------------------------------
// ep = enc_out @ Wd_top, emitted as bf16.
//   packed==1 (tier 3): rewrite A's 1KB row slots IN PLACE as
//     [512B bf16 enc | 512B bf16 ep]. Row-local -> in-place safe; enc_all
//     fully rewrites A each launch -> graph-replay safe.
//   packed==0 (tier 2): write bf16 ep rows to epOut, leave A untouched.
// Block = 32 rows, 256 threads; A staged fully in LDS before any write.
// ---------------------------------------------------------------------------
__global__ __launch_bounds__(256) void pack_ep(
    float* A, const float* __restrict__ W, u16* epOut, int packed)
{
    __shared__ float a_s[32 * 256];   // 32 KB
    const int m0   = blockIdx.x * 32;
    const int tid  = threadIdx.x;
    const int lane = tid & 63;
    const int rg   = tid >> 6;
    const int n0   = lane * 4;

    for (int v = tid; v < 32 * 64; v += 256)
        ((float4*)a_s)[v] = ((const float4*)(A + (size_t)m0 * 256))[v];
    __syncthreads();

    float4 acc[8];
    #pragma unroll
    for (int r = 0; r < 8; ++r) acc[r] = make_float4(0.f, 0.f, 0.f, 0.f);

    #pragma unroll 2
    for (int k = 0; k < 256; k += 4) {
        float4 wv[4];
        #pragma unroll
        for (int kk = 0; kk < 4; ++kk)
            wv[kk] = *(const float4*)&W[(size_t)(k + kk) * 256 + n0];
        float4 av[8];
        #pragma unroll
        for (int r = 0; r < 8; ++r)
            av[r] = *(const float4*)&a_s[(rg * 8 + r) * 256 + k];
        #pragma unroll
        for (int kk = 0; kk < 4; ++kk) {
            #pragma unroll
            for (int r = 0; r < 8; ++r) {
                float e = COMP(av[r], kk);
                acc[r].x += e * wv[kk].x; acc[r].y += e * wv[kk].y;
                acc[r].z += e * wv[kk].z; acc[r].w += e * wv[kk].w;
            }
        }
    }

    // ep bf16 write
    u16* epu = packed ? (u16*)A : epOut;
    #pragma unroll
    for (int r = 0; r < 8; ++r) {
        const size_t row = (size_t)(m0 + rg * 8 + r);
        ushort4 o;
        o.x = f2b_(acc[r].x); o.y = f2b_(acc[r].y);
        o.z = f2b_(acc[r].z); o.w = f2b_(acc[r].w);
        u16* dst = packed ? (epu + row * 512 + 256 + n0)
                          : (epu + row * 256 + n0);
        *(ushort4*)dst = o;
    }

    if (packed) {
        // rewrite the 32 enc rows as bf16 into the first 512B of each slot.
        // a_s holds the full fp32 copy; global A is only written, never
        // re-read, so no intra-block hazard.
        u32* ab = (u32*)A;
        for (int v = tid; v < 32 * 128; v += 256) {
            const int row = v >> 7, j = v & 127;
            float2 f = *(const float2*)&a_s[(row << 8) + (j << 1)];
            ab[((size_t)(m0 + row)) * 256 + j] = pack2_(f.x, f.y);
        }
    }
}

// ---------------------------------------------------------------------------
// Per-step decoder scores from precomputed fp32 ep (tier 1):
//   score[l,b] = Wl . tanh(ep[l,b,:] + hp[b,:])   (bl cancels in softmax)
// ---------------------------------------------------------------------------
__global__ __launch_bounds__(256) void scores_ep_f32(
    const float* __restrict__ ep, const float* __restrict__ hp,
    const float* __restrict__ Wl, float* __restrict__ scores)
{
    __shared__ float hp_s[8 * 256];
    const int b0  = blockIdx.x * 8;
    const int l0  = blockIdx.y * 20;
    const int tid = threadIdx.x;
    const int r   = tid >> 5;
    const int g   = tid & 31;

    for (int v = tid; v < 512; v += 256)
        ((float4*)hp_s)[v] = ((const float4*)(hp + (size_t)b0 * 256))[v];
    __syncthreads();

    const float4 wl0 = *(const float4*)&Wl[g * 4];
    const float4 wl1 = *(const float4*)&Wl[128 + g * 4];
    const float4 h0  = *(const float4*)&hp_s[r * 256 + g * 4];
    const float4 h1  = *(const float4*)&hp_s[r * 256 + 128 + g * 4];
    const float* eb  = ep + (size_t)l0 * (BB * 256) + (size_t)(b0 + r) * 256;

    #pragma unroll 2
    for (int li = 0; li < 20; ++li) {
        float4 e0 = *(const float4*)&eb[(size_t)li * (BB * 256) + g * 4];
        float4 e1 = *(const float4*)&eb[(size_t)li * (BB * 256) + 128 + g * 4];
        float p = tanhf_(e0.x + h0.x) * wl0.x + tanhf_(e0.y + h0.y) * wl0.y
                + tanhf_(e0.z + h0.z) * wl0.z + tanhf_(e0.w + h0.w) * wl0.w
                + tanhf_(e1.x + h1.x) * wl1.x + tanhf_(e1.y + h1.y) * wl1.y
                + tanhf_(e1.z + h1.z) * wl1.z + tanhf_(e1.w + h1.w) * wl1.w;
        #pragma unroll
        for (int msk = 16; msk >= 1; msk >>= 1) p += __shfl_xor(p, msk, 64);
        if (g == 0) scores[(size_t)(l0 + li) * BB + b0 + r] = p;
    }
}

// ---------------------------------------------------------------------------
// Same, from bf16 ep rows. sstr/soff (in u16 units) select the layout:
//   tier 3 packed slots: sstr=512, soff=256;  tier 2 dense: sstr=256, soff=0.
// ---------------------------------------------------------------------------
__global__ __launch_bounds__(256) void scores_ep_b16(
    const u16* __restrict__ ep, const float* __restrict__ hp,
    const float* __restrict__ Wl, float* __restrict__ scores,
    int sstr, int soff)
{
    __shared__ float hp_s[8 * 256];
    const int b0  = blockIdx.x * 8;
    const int l0  = blockIdx.y * 20;
    const int tid = threadIdx.x;
    const int r   = tid >> 5;
    const int g   = tid & 31;

    for (int v = tid; v < 512; v += 256)
        ((float4*)hp_s)[v] = ((const float4*)(hp + (size_t)b0 * 256))[v];
    __syncthreads();

    const float4 wl0 = *(const float4*)&Wl[g * 4];
    const float4 wl1 = *(const float4*)&Wl[128 + g * 4];
    const float4 h0  = *(const float4*)&hp_s[r * 256 + g * 4];
    const float4 h1  = *(const float4*)&hp_s[r * 256 + 128 + g * 4];

    #pragma unroll 2
    for (int li = 0; li < 20; ++li) {
        const u16* er = ep + ((size_t)(l0 + li) * BB + b0 + r) * sstr + soff;
        ushort4 u0 = *(const ushort4*)&er[g * 4];
        ushort4 u1 = *(const ushort4*)&er[128 + g * 4];
        float p = tanhf_(b2f_(u0.x) + h0.x) * wl0.x + tanhf_(b2f_(u0.y) + h0.y) * wl0.y
                + tanhf_(b2f_(u0.z) + h0.z) * wl0.z + tanhf_(b2f_(u0.w) + h0.w) * wl0.w
                + tanhf_(b2f_(u1.x) + h1.x) * wl1.x + tanhf_(b2f_(u1.y) + h1.y) * wl1.y
                + tanhf_(b2f_(u1.z) + h1.z) * wl1.z + tanhf_(b2f_(u1.w) + h1.w) * wl1.w;
        #pragma unroll
        for (int msk = 16; msk >= 1; msk >>= 1) p += __shfl_xor(p, msk, 64);
        if (g == 0) scores[(size_t)(l0 + li) * BB + b0 + r] = p;
    }
}

// ---------------------------------------------------------------------------
// softmax over L + ctx. fp32 enc variant (tiers 1/2). Block = 8 rows.
// ---------------------------------------------------------------------------
__global__ __launch_bounds__(256) void softmax_ctx(
    const float* __restrict__ scores, const float* __restrict__ enc_out,
    float* __restrict__ ctx)
{
    __shared__ float al_s[8 * 100];
    const int b0  = blockIdx.x * 8;
    const int tid = threadIdx.x;
    for (int v = tid; v < 800; v += 256) {
        int r = v / 100, l = v - r * 100;
        al_s[r * 100 + l] = scores[(size_t)l * BB + b0 + r];
    }
    __syncthreads();
    if (tid < 8) {
        float m = -1e30f;
        for (int l = 0; l < LL; ++l) m = fmaxf(m, al_s[tid * 100 + l]);
        float s = 0.f;
        for (int l = 0; l < LL; ++l) { float e = expf(al_s[tid * 100 + l] - m); al_s[tid * 100 + l] = e; s += e; }
        float inv = 1.f / s;
        for (int l = 0; l < LL; ++l) al_s[tid * 100 + l] *= inv;
    }
    __syncthreads();
    float acc[8] = {};
    for (int l = 0; l < LL; ++l) {
        const float* er = enc_out + (size_t)l * (BB * 256) + (size_t)b0 * 256 + tid;
        #pragma unroll
        for (int r = 0; r < 8; ++r) acc[r] += al_s[r * 100 + l] * er[r * 256];
    }
    for (int r = 0; r < 8; ++r) ctx[(size_t)(b0 + r) * 256 + tid] = acc[r];
}

// ---------------------------------------------------------------------------
// softmax over L + ctx, reading bf16 enc halves of the packed slots (tier 3).
// encp points at the packed buffer; slot (l,b) = 512 u16, enc = first 256.
// ---------------------------------------------------------------------------
__global__ __launch_bounds__(256) void softmax_ctx_b16(
    const float* __restrict__ scores, const u16* __restrict__ encp,
    float* __restrict__ ctx)
{
    __shared__ float al_s[8 * 100];
    const int b0  = blockIdx.x * 8;
    const int tid = threadIdx.x;
    for (int v = tid; v < 800; v += 256) {
        int r = v / 100, l = v - r * 100;
        al_s[r * 100 + l] = scores[(size_t)l * BB + b0 + r];
    }
    __syncthreads();
    if (tid < 8) {
        float m = -1e30f;
        for (int l = 0; l < LL; ++l) m = fmaxf(m, al_s[tid * 100 + l]);
        float s = 0.f;
        for (int l = 0; l < LL; ++l) { float e = expf(al_s[tid * 100 + l] - m); al_s[tid * 100 + l] = e; s += e; }
        float inv = 1.f / s;
        for (int l = 0; l < LL; ++l) al_s[tid * 100 + l] *= inv;
    }
    __syncthreads();
    float acc[8] = {};
    for (int l = 0; l < LL; ++l) {
        const u16* er = encp + ((size_t)l * BB + b0) * 512 + tid;
        #pragma unroll
        for (int r = 0; r < 8; ++r) acc[r] += al_s[r * 100 + l] * b2f_(er[r * 512]);
    }
    for (int r = 0; r < 8; ++r) ctx[(size_t)(b0 + r) * 256 + tid] = acc[r];
}

// ---------------------------------------------------------------------------
// Decoder LSTM cell: grid 256 x 512, block = 8 rows, half0 = ctx@Wdi,
// half1 = hd@Wdh, coalesced float4 weights. hd updated in place.
// ---------------------------------------------------------------------------
__global__ __launch_bounds__(512) void dec_step(
    const float* __restrict__ ctxp,
    const float* __restrict__ Wdi, const float* __restrict__ Wdh,
    const float* __restrict__ bdec,
    float* __restrict__ hd, float* __restrict__ c_st, int first)
{
    __shared__ float ct_s[8 * 256];        // 8 KB
    __shared__ float hd_s[8 * 256];        // 8 KB
    __shared__ float gate_s[2][8 * 1024];  // 64 KB
    const int row0 = blockIdx.x * 8;
    const int tid  = threadIdx.x;
    const int lane = tid & 63, w = tid >> 6;
    const int half = tid >> 8;
    const int ct   = tid & 255;
    const int c0   = ct * 4;

    ((float4*)ct_s)[tid] = ((const float4*)(ctxp + (size_t)row0 * 256))[tid];
    if (!first)
        ((float4*)hd_s)[tid] = ((const float4*)(hd + (size_t)row0 * 256))[tid];
    __syncthreads();

    float4 acc[8];
    {
        float4 b4 = *(const float4*)&bdec[c0];
        float4 bias4 = (half == 0) ? b4 : make_float4(0.f, 0.f, 0.f, 0.f);
        #pragma unroll
        for (int r = 0; r < 8; ++r) acc[r] = bias4;
    }
    if (half == 0) {
        const float* wP = Wdi + c0;
        #pragma unroll 2
        for (int ch = 0; ch < 64; ++ch) {
            const int k0 = ch * 4;
            float4 w0 = *(const float4*)&wP[(size_t)(k0 + 0) * 1024];
            float4 w1 = *(const float4*)&wP[(size_t)(k0 + 1) * 1024];
            float4 w2 = *(const float4*)&wP[(size_t)(k0 + 2) * 1024];
            float4 w3 = *(const float4*)&wP[(size_t)(k0 + 3) * 1024];
            #pragma unroll
            for (int r = 0; r < 8; ++r) {
                float4 av = *(const float4*)&ct_s[r * 256 + k0];
                acc[r].x += av.x * w0.x; acc[r].y += av.x * w0.y;
                acc[r].z += av.x * w0.z; acc[r].w += av.x * w0.w;
                acc[r].x += av.y * w1.x; acc[r].y += av.y * w1.y;
                acc[r].z += av.y * w1.z; acc[r].w += av.y * w1.w;
                acc[r].x += av.z * w2.x; acc[r].y += av.z * w2.y;
                acc[r].z += av.z * w2.z; acc[r].w += av.z * w2.w;
                acc[r].x += av.w * w3.x; acc[r].y += av.w * w3.y;
                acc[r].z += av.w * w3.z; acc[r].w += av.w * w3.w;
            }
        }
    } else if (!first) {
        const float* wP = Wdh + c0;
        #pragma unroll 2
        for (int ch = 0; ch < 64; ++ch) {
            const int k0 = ch * 4;
            float4 w0 = *(const float4*)&wP[(size_t)(k0 + 0) * 1024];
            float4 w1 = *(const float4*)&wP[(size_t)(k0 + 1) * 1024];
            float4 w2 = *(const float4*)&wP[(size_t)(k0 + 2) * 1024];
            float4 w3 = *(const float4*)&wP[(size_t)(k0 + 3) * 1024];
            #pragma unroll
            for (int r = 0; r < 8; ++r) {
                float4 av = *(const float4*)&hd_s[r * 256 + k0];
                acc[r].x += av.x * w0.x; acc[r].y += av.x * w0.y;
                acc[r].z += av.x * w0.z; acc[r].w += av.x * w0.w;
                acc[r].x += av.y * w1.x; acc[r].y += av.y * w1.y;
                acc[r].z += av.y * w1.z; acc[r].w += av.y * w1.w;
                acc[r].x += av.z * w2.x; acc[r].y += av.z * w2.y;
                acc[r].z += av.z * w2.z; acc[r].w += av.z * w2.w;
                acc[r].x += av.w * w3.x; acc[r].y += av.w * w3.y;
                acc[r].z += av.w * w3.z; acc[r].w += av.w * w3.w;
            }
        }
    }
    #pragma unroll
    for (int r = 0; r < 8; ++r)
        *(float4*)&gate_s[half][r * 1024 + c0] = acc[r];
    __syncthreads();

    // epilogue: wave-local row w, lane -> 4 units
    {
        const float* g0 = &gate_s[0][w * 1024 + lane * 4];
        const float* g1 = &gate_s[1][w * 1024 + lane * 4];
        float4 giA = *(const float4*)&g0[0],   giB = *(const float4*)&g1[0];
        float4 gfA = *(const float4*)&g0[256], gfB = *(const float4*)&g1[256];
        float4 ggA = *(const float4*)&g0[512], ggB = *(const float4*)&g1[512];
        float4 goA = *(const float4*)&g0[768], goB = *(const float4*)&g1[768];
        size_t ci = (size_t)(row0 + w) * 256 + lane * 4;
        float4 c4 = first ? make_float4(0.f, 0.f, 0.f, 0.f)
                          : *(const float4*)&c_st[ci];
        float cc[4] = { c4.x, c4.y, c4.z, c4.w };
        float gi[4] = { giA.x + giB.x, giA.y + giB.y, giA.z + giB.z, giA.w + giB.w };
        float gf[4] = { gfA.x + gfB.x, gfA.y + gfB.y, gfA.z + gfB.z, gfA.w + gfB.w };
        float gg[4] = { ggA.x + ggB.x, ggA.y + ggB.y, ggA.z + ggB.z, ggA.w + ggB.w };
        float go[4] = { goA.x + goB.x, goA.y + goB.y, goA.z + goB.z, goA.w + goB.w };
        float4 cn, hn;
        #pragma unroll
        for (int uu = 0; uu < 4; ++uu) {
            float cv = sigmoidf_(gf[uu]) * cc[uu] + sigmoidf_(gi[uu]) * tanhf_(gg[uu]);
            float hv = sigmoidf_(go[uu]) * tanhf_(cv);
            if (uu == 0) { cn.x = cv; hn.x = hv; } else if (uu == 1) { cn.y = cv; hn.y = hv; }
            else if (uu == 2) { cn.z = cv; hn.z = hv; } else { cn.w = cv; hn.w = hv; }
        }
        *(float4*)&c_st[ci] = cn;
        *(float4*)&hd[ci]   = hn;
    }
}

// ---------------------------------------------------------------------------
// Head: fc = tanh(h_d@Wf+bf); out[:,step] = tanh(fc@Wo+bo). Block = 16 rows.
// ---------------------------------------------------------------------------
__global__ __launch_bounds__(256) void head_k(
    const float* __restrict__ hd, const float* __restrict__ Wf,
    const float* __restrict__ bf, const float* __restrict__ Wo,
    const float* __restrict__ bo, float* __restrict__ out, int step)
{
    __shared__ float hd_s[16 * 256];
    __shared__ float fc_s[16 * 128];
    const int b0  = blockIdx.x * 16;
    const int tid = threadIdx.x;
    {
        const float4* hg = (const float4*)(hd + (size_t)b0 * 256);
        for (int i = tid; i < 1024; i += 256) ((float4*)hd_s)[i] = hg[i];
    }
    __syncthreads();
    {
        const int f = tid & 127, rg = tid >> 7;
        float acc[8];
        float bfv = bf[f];
        #pragma unroll
        for (int rr = 0; rr < 8; ++rr) acc[rr] = bfv;
        const float* wp = Wf + f;
        #pragma unroll 2
        for (int k = 0; k < 256; ++k) {
            float wv = wp[k * 128];
            #pragma unroll
            for (int rr = 0; rr < 8; ++rr) acc[rr] += hd_s[(rg * 8 + rr) * 256 + k] * wv;
        }
        for (int rr = 0; rr < 8; ++rr) fc_s[(rg * 8 + rr) * 128 + f] = tanhf_(acc[rr]);
    }
    __syncthreads();
    {
        const int lane = tid & 63, w = tid >> 6;
        const float bov = bo[0];
        #pragma unroll
        for (int rr = 0; rr < 4; ++rr) {
            int r = w * 4 + rr;
            float p = fc_s[r * 128 + lane] * Wo[lane] + fc_s[r * 128 + 64 + lane] * Wo[64 + lane];
            #pragma unroll
            for (int msk = 32; msk >= 1; msk >>= 1) p += __shfl_xor(p, msk, 64);
            if (lane == 0) out[(size_t)(b0 + r) * NOUT + step] = tanhf_(p + bov);
        }
    }
}

extern "C" void kernel_launch(void* const* d_in, const int* in_sizes, int n_in,
                              void* d_out, int out_size, void* d_ws, size_t ws_size,
                              hipStream_t stream)
{
    const float* x    = (const float*)d_in[0];
    const float* Wa   = (const float*)d_in[1];
    const float* ba   = (const float*)d_in[2];
    const float* Wi   = (const float*)d_in[3];
    const float* Wh   = (const float*)d_in[4];
    const float* be   = (const float*)d_in[5];
    const float* Wd   = (const float*)d_in[6];
    const float* bd   = (const float*)d_in[7];
    const float* Wl   = (const float*)d_in[8];
    const float* bl   = (const float*)d_in[9];
    const float* Wdi  = (const float*)d_in[10];
    const float* Wdh  = (const float*)d_in[11];
    const float* bdec = (const float*)d_in[12];
    const float* Wf   = (const float*)d_in[13];
    const float* bf   = (const float*)d_in[14];
    const float* Wo   = (const float*)d_in[15];
    const float* bo   = (const float*)d_in[16];
    float* out = (float*)d_out;

    // ws layout (floats): enc_out(/packed) | hd | c_d | ctx(=hp alias) | scores | [ep]
    const size_t f_enc    = (size_t)LL * BB * EE;     // 52,428,800
    const size_t f_state  = (size_t)BB * EE;          // 524,288
    const size_t f_scores = (size_t)LL * BB;          // 204,800
    const size_t need3 = (f_enc + 3 * f_state + f_scores) * sizeof(float); // == old need_base, known to fit
    const size_t need2 = need3 + f_enc * sizeof(u16);                      // + bf16 ep (~307 MiB)
    const size_t need1 = need3 + f_enc * sizeof(float);                    // + fp32 ep (~407 MiB)

    float* ws      = (float*)d_ws;
    float* enc_out = ws;
    float* hd      = enc_out + f_enc;
    float* c_d     = hd + f_state;
    float* ctx     = c_d + f_state;      // also hp: disjoint lifetimes within a step
    float* scores  = ctx + f_state;
    float* ep32    = scores + f_scores;  // tier 1 only
    u16*   ep16    = (u16*)(scores + f_scores);  // tier 2 only
    float* hp      = ctx;

    if (ws_size < need3) return;   // diagnostic clean-fail (known satisfied)
    const int tier = (ws_size >= need1) ? 1 : (ws_size >= need2) ? 2 : 3;

    // persistent encoder: one dispatch, 1024-thread blocks (4 waves/SIMD)
    enc_all<<<BB / 8, 1024, 0, stream>>>(x, Wa, ba, Wi, Wh, be, enc_out);

    // hoist the step-invariant enc_out @ Wd_top out of the decode loop
    if (tier == 1)
        gemm_nk256<<<(LL * BB) / 32, 256, 0, stream>>>(
            enc_out, Wd, (const float*)nullptr, ep32, 0);
    else
        pack_ep<<<(LL * BB) / 32, 256, 0, stream>>>(
            enc_out, Wd, ep16, tier == 3 ? 1 : 0);

    for (int s = 0; s < NOUT; ++s) {
        // hp = hd @ Wd_bot + bd  (step 0: hd == 0 -> hp = bd)
        gemm_nk256<<<BB / 32, 256, 0, stream>>>(
            hd, Wd + 256 * 256, bd, hp, s == 0);
        if (tier == 1)
            scores_ep_f32<<<dim3(BB / 8, 5), 256, 0, stream>>>(ep32, hp, Wl, scores);
        else if (tier == 2)
            scores_ep_b16<<<dim3(BB / 8, 5), 256, 0, stream>>>(ep16, hp, Wl, scores, 256, 0);
        else
            scores_ep_b16<<<dim3(BB / 8, 5), 256, 0, stream>>>(
                (const u16*)enc_out, hp, Wl, scores, 512, 256);
        if (tier == 3)
            softmax_ctx_b16<<<BB / 8, 256, 0, stream>>>(scores, (const u16*)enc_out, ctx);
        else
            softmax_ctx<<<BB / 8, 256, 0, stream>>>(scores, enc_out, ctx);
        dec_step<<<BB / 8, 512, 0, stream>>>(ctx, Wdi, Wdh, bdec, hd, c_d, s == 0);
        head_k<<<BB / 16, 256, 0, stream>>>(hd, Wf, bf, Wo, bo, out, s);
    }
}

// Round 3
// 2852.448 us; speedup vs baseline: 1.5571x; 1.3185x over previous
//
#include <hip/hip_runtime.h>
#include <math.h>

// Problem constants
#define BB 2048
#define LL 100
#define FF 64
#define EE 256
#define DD 256
#define NOUT 3

#define COMP(v, i) ((i) == 0 ? (v).x : (i) == 1 ? (v).y : (i) == 2 ? (v).z : (v).w)

typedef unsigned short u16;
typedef unsigned int u32;
typedef __attribute__((ext_vector_type(8))) __bf16 bf16x8;
typedef __attribute__((ext_vector_type(4))) float f32x4;

__device__ __forceinline__ float sigmoidf_(float x) {
    return 1.0f / (1.0f + expf(-x));
}
// tanh via identity 1 - 2/(1+e^{2x}); ~2e-7 abs fp32 error, saturates correctly.
__device__ __forceinline__ float tanhf_(float x) {
    return 1.0f - 2.0f / (1.0f + expf(2.0f * x));
}
// fp32 -> bf16 round-to-nearest-even
__device__ __forceinline__ u16 f2b_(float f) {
    u32 u = __float_as_uint(f);
    u = (u + 0x7FFFu + ((u >> 16) & 1u)) >> 16;
    return (u16)u;
}
__device__ __forceinline__ float b2f_(u16 b) {
    return __uint_as_float(((u32)b) << 16);
}
__device__ __forceinline__ f32x4 splat4(float b) {
    f32x4 v; v[0] = b; v[1] = b; v[2] = b; v[3] = b; return v;
}
// split 8 fp32 into bf16 hi/lo planes packed as uint4 (little-endian pairs)
__device__ __forceinline__ void split8(const float* v, uint4& H, uint4& L) {
    u16 h[8], lo[8];
    #pragma unroll
    for (int e = 0; e < 8; ++e) {
        h[e]  = f2b_(v[e]);
        lo[e] = f2b_(v[e] - b2f_(h[e]));
    }
    H = make_uint4((u32)h[0]  | ((u32)h[1]  << 16), (u32)h[2]  | ((u32)h[3]  << 16),
                   (u32)h[4]  | ((u32)h[5]  << 16), (u32)h[6]  | ((u32)h[7]  << 16));
    L = make_uint4((u32)lo[0] | ((u32)lo[1] << 16), (u32)lo[2] | ((u32)lo[3] << 16),
                   (u32)lo[4] | ((u32)lo[5] << 16), (u32)lo[6] | ((u32)lo[7] << 16));
}

// A-fragment LDS index: [mt][kt][plane][lane][8] u16
#define AF(mt, kt, p, ln) (((((mt) * 10 + (kt)) * 2 + (p)) * 64 + (ln)) * 8)

// ---------------------------------------------------------------------------
// Weight prep (once per launch, ~1.36 MB into the dead ctx region):
// bf16 hi/lo split of [Wi;Wh] (tiles 0..639) and Wa (tiles 640..679) in MFMA
// B-fragment order. Tile (nt,kt) = 1024 u16: plane-hi [64 lanes][8 e], then lo.
// Element (lane l, e) = W[k = kt*32 + (l>>4)*8 + e][col = nt*16 + (l&15)].
// k-permutation is shared by A-frag staging, so any hardware k-map is exact.
// ---------------------------------------------------------------------------
__global__ __launch_bounds__(64) void w_prep(
    const float* __restrict__ Wi, const float* __restrict__ Wh,
    const float* __restrict__ Wa, u16* __restrict__ wp)
{
    const int bid = blockIdx.x;      // 0..679
    const int l   = threadIdx.x;     // 0..63
    const int isA = (bid >= 640);
    const int b2  = isA ? bid - 640 : bid;
    const int nt  = b2 / 10, kt = b2 - nt * 10;
    const int col = nt * 16 + (l & 15);

    float v[8];
    #pragma unroll
    for (int e = 0; e < 8; ++e) {
        const int k = kt * 32 + ((l >> 4) << 3) + e;
        v[e] = isA ? Wa[(size_t)k * 64 + col]
                   : (k < 64 ? Wi[(size_t)k * 1024 + col]
                             : Wh[(size_t)(k - 64) * 1024 + col]);
    }
    uint4 H, L;
    split8(v, H, L);
    *(uint4*)&wp[(size_t)bid * 1024 + (size_t)l * 8]       = H;
    *(uint4*)&wp[(size_t)bid * 1024 + 512 + (size_t)l * 8] = L;
}

// ---------------------------------------------------------------------------
// Persistent MFMA encoder. grid 64 x 1024 threads (16 waves, 4/SIMD).
// Block owns 32 rows (2 M-tiles of 16) for all 100 timesteps.
// Arithmetic: split-bf16 (hi+lo) x 3 MFMA passes -> ~fp32 precision.
// Per t: P0 stage x-frags -> P1 attention MFMA (waves 0-3) -> P2 wave-parallel
// softmax + ein-frags -> P3 gate MFMA (all 16 waves; wave w owns N-tiles
// {w, w+16, w+32, w+48} = gates i/f/g/o of units 16w..16w+15) -> in-wave LSTM
// epilogue (c in regs) -> h-frag scatter for t+1. 4 barriers/t.
// ---------------------------------------------------------------------------
__global__ __launch_bounds__(1024) void enc_mfma(
    const float* __restrict__ x,
    const float* __restrict__ ba, const float* __restrict__ be,
    const u16* __restrict__ wp,
    float* __restrict__ enc_out)
{
    __shared__ u16   aFrag[2 * 10 * 2 * 64 * 8];  // 40 KB  A-fragments (bf16 hi/lo)
    __shared__ float x_s[32 * 68];                // 8.5 KB x fp32 (padded stride 68)
    __shared__ float e_s[32 * 68];                // 8.5 KB attention energies

    const int row0 = blockIdx.x * 32;
    const int tid  = threadIdx.x;
    const int l    = tid & 63;
    const int w    = tid >> 6;            // wave 0..15
    const int u    = (w << 4) + (l & 15); // gate unit owned by this lane (0..255)

    // zero h-fragment region (t=0: h == 0). Zero everything, x region is
    // rewritten in P0 anyway.
    for (int v = tid; v < 2 * 10 * 2 * 64 * 8 / 2; v += 1024)
        ((u32*)aFrag)[v] = 0u;

    // biases: acc column = nt*16 + (l&15); nt = w + 16*j
    float be_r[4];
    #pragma unroll
    for (int j = 0; j < 4; ++j) be_r[j] = be[(size_t)(w + 16 * j) * 16 + (l & 15)];
    const float ba_r = (w < 4) ? ba[(w << 4) + (l & 15)] : 0.f;

    float c_state[8];
    #pragma unroll
    for (int i = 0; i < 8; ++i) c_state[i] = 0.f;

    __syncthreads();

    for (int t = 0; t < LL; ++t) {
        // ---- P0: stage x_t fragments + fp32 copy (threads 0..255) ----
        if (tid < 256) {
            const int kt2 = tid >> 7;          // 0..1
            const int mt  = (tid >> 6) & 1;    // 0..1
            const int l2  = tid & 63;
            const int row2 = mt * 16 + (l2 & 15);
            const int f0   = kt2 * 32 + ((l2 >> 4) << 3);
            const float* xp = x + (size_t)(row0 + row2) * (LL * FF) + (size_t)t * FF + f0;
            float4 xa = *(const float4*)xp;
            float4 xb = *(const float4*)(xp + 4);
            float v[8] = {xa.x, xa.y, xa.z, xa.w, xb.x, xb.y, xb.z, xb.w};
            uint4 H, L;
            split8(v, H, L);
            *(uint4*)&aFrag[AF(mt, kt2, 0, l2)] = H;
            *(uint4*)&aFrag[AF(mt, kt2, 1, l2)] = L;
            *(float4*)&x_s[row2 * 68 + f0]     = xa;
            *(float4*)&x_s[row2 * 68 + f0 + 4] = xb;
        }
        __syncthreads();   // A: x-frags + h-frags(t-1) visible

        // ---- P1: attention energies via MFMA (waves 0..3, N-tile = w) ----
        if (w < 4) {
            f32x4 ea0 = splat4(ba_r), ea1 = splat4(ba_r);
            #pragma unroll 2
            for (int kt = 0; kt < 10; ++kt) {
                bf16x8 Ah0 = *(const bf16x8*)&aFrag[AF(0, kt, 0, l)];
                bf16x8 Al0 = *(const bf16x8*)&aFrag[AF(0, kt, 1, l)];
                bf16x8 Ah1 = *(const bf16x8*)&aFrag[AF(1, kt, 0, l)];
                bf16x8 Al1 = *(const bf16x8*)&aFrag[AF(1, kt, 1, l)];
                const size_t o = (size_t)(640 + w * 10 + kt) * 1024 + (size_t)l * 8;
                bf16x8 Bh = *(const bf16x8*)&wp[o];
                bf16x8 Bl = *(const bf16x8*)&wp[o + 512];
                ea0 = __builtin_amdgcn_mfma_f32_16x16x32_bf16(Ah0, Bh, ea0, 0, 0, 0);
                ea1 = __builtin_amdgcn_mfma_f32_16x16x32_bf16(Ah1, Bh, ea1, 0, 0, 0);
                ea0 = __builtin_amdgcn_mfma_f32_16x16x32_bf16(Al0, Bh, ea0, 0, 0, 0);
                ea1 = __builtin_amdgcn_mfma_f32_16x16x32_bf16(Al1, Bh, ea1, 0, 0, 0);
                ea0 = __builtin_amdgcn_mfma_f32_16x16x32_bf16(Ah0, Bl, ea0, 0, 0, 0);
                ea1 = __builtin_amdgcn_mfma_f32_16x16x32_bf16(Ah1, Bl, ea1, 0, 0, 0);
            }
            const int colA = (w << 4) + (l & 15);
            #pragma unroll
            for (int r = 0; r < 4; ++r) {
                const int rowT = ((l >> 4) << 2) + r;
                e_s[(rowT)      * 68 + colA] = tanhf_(ea0[r]);
                e_s[(16 + rowT) * 68 + colA] = tanhf_(ea1[r]);
            }
        }
        __syncthreads();   // B: energies staged

        // ---- P2: softmax over 64 cols + ein fragments (threads 0..511) ----
        if (tid < 512) {
            const int row2 = tid >> 4;           // 0..31
            const int c4   = (tid & 15) * 4;     // 0..60
            float4 ev = *(const float4*)&e_s[row2 * 68 + c4];
            float m = fmaxf(fmaxf(ev.x, ev.y), fmaxf(ev.z, ev.w));
            #pragma unroll
            for (int msk = 8; msk >= 1; msk >>= 1) m = fmaxf(m, __shfl_xor(m, msk, 64));
            float4 ex;
            ex.x = expf(ev.x - m); ex.y = expf(ev.y - m);
            ex.z = expf(ev.z - m); ex.w = expf(ev.w - m);
            float s = ex.x + ex.y + ex.z + ex.w;
            #pragma unroll
            for (int msk = 8; msk >= 1; msk >>= 1) s += __shfl_xor(s, msk, 64);
            const float inv = 1.f / s;
            float4 xv = *(const float4*)&x_s[row2 * 68 + c4];
            float ein[4] = { ex.x * inv * xv.x, ex.y * inv * xv.y,
                             ex.z * inv * xv.z, ex.w * inv * xv.w };
            // fragment placement: 4 consecutive k -> same lane slot, e0..e0+3
            const int mt   = row2 >> 4;
            const int rowT = row2 & 15;
            const int kt   = c4 >> 5;
            const int g2   = (c4 & 31) >> 3;
            const int e0   = c4 & 7;             // 0 or 4
            const int ln   = rowT + (g2 << 4);
            ushort4 h4, l4;
            #pragma unroll
            for (int e = 0; e < 4; ++e) {
                u16 hh = f2b_(ein[e]);
                u16 ll = f2b_(ein[e] - b2f_(hh));
                if (e == 0) { h4.x = hh; l4.x = ll; } else if (e == 1) { h4.y = hh; l4.y = ll; }
                else if (e == 2) { h4.z = hh; l4.z = ll; } else { h4.w = hh; l4.w = ll; }
            }
            *(ushort4*)&aFrag[AF(mt, kt, 0, ln) + e0] = h4;
            *(ushort4*)&aFrag[AF(mt, kt, 1, ln) + e0] = l4;
        }
        __syncthreads();   // C: ein-frags staged

        // ---- P3: gate GEMM. wave w: N-tiles w+16j (j=0..3 -> i,f,g,o) ----
        f32x4 acc[2][4];
        #pragma unroll
        for (int mt = 0; mt < 2; ++mt)
            #pragma unroll
            for (int j = 0; j < 4; ++j) acc[mt][j] = splat4(be_r[j]);

        #pragma unroll 2
        for (int kt = 0; kt < 10; ++kt) {
            bf16x8 Ah0 = *(const bf16x8*)&aFrag[AF(0, kt, 0, l)];
            bf16x8 Al0 = *(const bf16x8*)&aFrag[AF(0, kt, 1, l)];
            bf16x8 Ah1 = *(const bf16x8*)&aFrag[AF(1, kt, 0, l)];
            bf16x8 Al1 = *(const bf16x8*)&aFrag[AF(1, kt, 1, l)];
            #pragma unroll
            for (int j = 0; j < 4; ++j) {
                const size_t o = (size_t)((w + 16 * j) * 10 + kt) * 1024 + (size_t)l * 8;
                bf16x8 Bh = *(const bf16x8*)&wp[o];
                bf16x8 Bl = *(const bf16x8*)&wp[o + 512];
                acc[0][j] = __builtin_amdgcn_mfma_f32_16x16x32_bf16(Ah0, Bh, acc[0][j], 0, 0, 0);
                acc[1][j] = __builtin_amdgcn_mfma_f32_16x16x32_bf16(Ah1, Bh, acc[1][j], 0, 0, 0);
                acc[0][j] = __builtin_amdgcn_mfma_f32_16x16x32_bf16(Al0, Bh, acc[0][j], 0, 0, 0);
                acc[1][j] = __builtin_amdgcn_mfma_f32_16x16x32_bf16(Al1, Bh, acc[1][j], 0, 0, 0);
                acc[0][j] = __builtin_amdgcn_mfma_f32_16x16x32_bf16(Ah0, Bl, acc[0][j], 0, 0, 0);
                acc[1][j] = __builtin_amdgcn_mfma_f32_16x16x32_bf16(Ah1, Bl, acc[1][j], 0, 0, 0);
            }
        }

        // ---- epilogue: in-wave LSTM cell update; c in registers ----
        float hval[8];
        #pragma unroll
        for (int mt = 0; mt < 2; ++mt) {
            #pragma unroll
            for (int r = 0; r < 4; ++r) {
                const float gi = acc[mt][0][r], gf = acc[mt][1][r];
                const float gg = acc[mt][2][r], go = acc[mt][3][r];
                float cv = sigmoidf_(gf) * c_state[mt * 4 + r]
                         + sigmoidf_(gi) * tanhf_(gg);
                c_state[mt * 4 + r] = cv;
                const float hv = sigmoidf_(go) * tanhf_(cv);
                hval[mt * 4 + r] = hv;
                const int rowT = ((l >> 4) << 2) + r;
                enc_out[((size_t)t * BB + row0 + mt * 16 + rowT) * 256 + u] = hv;
            }
        }
        __syncthreads();   // D: all P3 reads of aFrag done; safe to rewrite h

        // h fragments for t+1: k_global = 64+u
        {
            const int kt_h = 2 + (u >> 5);
            const int g2   = (u & 31) >> 3;
            const int e    = u & 7;
            #pragma unroll
            for (int mt = 0; mt < 2; ++mt) {
                #pragma unroll
                for (int r = 0; r < 4; ++r) {
                    const int rowT = ((l >> 4) << 2) + r;
                    const int ln   = rowT + (g2 << 4);
                    const float hv = hval[mt * 4 + r];
                    const u16 hh = f2b_(hv);
                    aFrag[AF(mt, kt_h, 0, ln) + e] = hh;
                    aFrag[AF(mt, kt_h, 1, ln) + e] = f2b_(hv - b2f_(hh));
                }
            }
        }
        // next-iter barrier A orders h/x-frag writes before P1/P3 reads.
    }
}

// ---------------------------------------------------------------------------
// Generic fp32 GEMM C(M,256) = A(M,256) @ W(256,256) [+ bias].
// Block = 32 rows, 256 threads. skip_gemm: C = bias (decoder step 0, hd==0).
// Used for: hp = hd @ Wd_bot + bd   and (tier1) ep32 = enc_out @ Wd_top.
// ---------------------------------------------------------------------------
__global__ __launch_bounds__(256) void gemm_nk256(
    const float* __restrict__ A, const float* __restrict__ W,
    const float* __restrict__ bias, float* __restrict__ C, int skip_gemm)
{
    __shared__ float a_s[32 * 256];   // 32 KB
    const int m0   = blockIdx.x * 32;
    const int tid  = threadIdx.x;
    const int lane = tid & 63;
    const int rg   = tid >> 6;        // 0..3 -> rows rg*8..rg*8+7
    const int n0   = lane * 4;

    float4 bias4 = make_float4(0.f, 0.f, 0.f, 0.f);
    if (bias) bias4 = *(const float4*)&bias[n0];

    if (skip_gemm) {
        #pragma unroll
        for (int r = 0; r < 8; ++r)
            *(float4*)&C[(size_t)(m0 + rg * 8 + r) * 256 + n0] = bias4;
        return;
    }

    for (int v = tid; v < 32 * 64; v += 256)
        ((float4*)a_s)[v] = ((const float4*)(A + (size_t)m0 * 256))[v];
    __syncthreads();

    float4 acc[8];
    #pragma unroll
    for (int r = 0; r < 8; ++r) acc[r] = bias4;

    #pragma unroll 2
    for (int k = 0; k < 256; k += 4) {
        float4 wv[4];
        #pragma unroll
        for (int kk = 0; kk < 4; ++kk)
            wv[kk] = *(const float4*)&W[(size_t)(k + kk) * 256 + n0];
        float4 av[8];
        #pragma unroll
        for (int r = 0; r < 8; ++r)
            av[r] = *(const float4*)&a_s[(rg * 8 + r) * 256 + k];
        #pragma unroll
        for (int kk = 0; kk < 4; ++kk) {
            #pragma unroll
            for (int r = 0; r < 8; ++r) {
                float e = COMP(av[r], kk);
                acc[r].x += e * wv[kk].x; acc[r].y += e * wv[kk].y;
                acc[r].z += e * wv[kk].z; acc[r].w += e * wv[kk].w;
            }
        }
    }
    #pragma unroll
    for (int r = 0; r < 8; ++r)
        *(float4*)&C[(size_t)(m0 + rg * 8 + r) * 256 + n0] = acc[r];
}

// ---------------------------------------------------------------------------
// ep = enc_out @ Wd_top, emitted as bf16 (tiers 2/3 fallback).
// ---------------------------------------------------------------------------
__global__ __launch_bounds__(256) void pack_ep(
    float* A, const float* __restrict__ W, u16* epOut, int packed)
{
    __shared__ float a_s[32 * 256];   // 32 KB
    const int m0   = blockIdx.x * 32;
    const int tid  = threadIdx.x;
    const int lane = tid & 63;
    const int rg   = tid >> 6;
    const int n0   = lane * 4;

    for (int v = tid; v < 32 * 64; v += 256)
        ((float4*)a_s)[v] = ((const float4*)(A + (size_t)m0 * 256))[v];
    __syncthreads();

    float4 acc[8];
    #pragma unroll
    for (int r = 0; r < 8; ++r) acc[r] = make_float4(0.f, 0.f, 0.f, 0.f);

    #pragma unroll 2
    for (int k = 0; k < 256; k += 4) {
        float4 wv[4];
        #pragma unroll
        for (int kk = 0; kk < 4; ++kk)
            wv[kk] = *(const float4*)&W[(size_t)(k + kk) * 256 + n0];
        float4 av[8];
        #pragma unroll
        for (int r = 0; r < 8; ++r)
            av[r] = *(const float4*)&a_s[(rg * 8 + r) * 256 + k];
        #pragma unroll
        for (int kk = 0; kk < 4; ++kk) {
            #pragma unroll
            for (int r = 0; r < 8; ++r) {
                float e = COMP(av[r], kk);
                acc[r].x += e * wv[kk].x; acc[r].y += e * wv[kk].y;
                acc[r].z += e * wv[kk].z; acc[r].w += e * wv[kk].w;
            }
        }
    }

    u16* epu = packed ? (u16*)A : epOut;
    #pragma unroll
    for (int r = 0; r < 8; ++r) {
        const size_t row = (size_t)(m0 + rg * 8 + r);
        ushort4 o;
        o.x = f2b_(acc[r].x); o.y = f2b_(acc[r].y);
        o.z = f2b_(acc[r].z); o.w = f2b_(acc[r].w);
        u16* dst = packed ? (epu + row * 512 + 256 + n0)
                          : (epu + row * 256 + n0);
        *(ushort4*)dst = o;
    }

    if (packed) {
        u32* ab = (u32*)A;
        for (int v = tid; v < 32 * 128; v += 256) {
            const int row = v >> 7, j = v & 127;
            float2 f = *(const float2*)&a_s[(row << 8) + (j << 1)];
            u16 h0 = f2b_(f.x), h1 = f2b_(f.y);
            ab[((size_t)(m0 + row)) * 256 + j] = (u32)h0 | ((u32)h1 << 16);
        }
    }
}

// ---------------------------------------------------------------------------
// Per-step decoder scores from precomputed fp32 ep (tier 1):
//   score[l,b] = Wl . tanh(ep[l,b,:] + hp[b,:])   (bl cancels in softmax)
// ---------------------------------------------------------------------------
__global__ __launch_bounds__(256) void scores_ep_f32(
    const float* __restrict__ ep, const float* __restrict__ hp,
    const float* __restrict__ Wl, float* __restrict__ scores)
{
    __shared__ float hp_s[8 * 256];
    const int b0  = blockIdx.x * 8;
    const int l0  = blockIdx.y * 20;
    const int tid = threadIdx.x;
    const int r   = tid >> 5;
    const int g   = tid & 31;

    for (int v = tid; v < 512; v += 256)
        ((float4*)hp_s)[v] = ((const float4*)(hp + (size_t)b0 * 256))[v];
    __syncthreads();

    const float4 wl0 = *(const float4*)&Wl[g * 4];
    const float4 wl1 = *(const float4*)&Wl[128 + g * 4];
    const float4 h0  = *(const float4*)&hp_s[r * 256 + g * 4];
    const float4 h1  = *(const float4*)&hp_s[r * 256 + 128 + g * 4];
    const float* eb  = ep + (size_t)l0 * (BB * 256) + (size_t)(b0 + r) * 256;

    #pragma unroll 2
    for (int li = 0; li < 20; ++li) {
        float4 e0 = *(const float4*)&eb[(size_t)li * (BB * 256) + g * 4];
        float4 e1 = *(const float4*)&eb[(size_t)li * (BB * 256) + 128 + g * 4];
        float p = tanhf_(e0.x + h0.x) * wl0.x + tanhf_(e0.y + h0.y) * wl0.y
                + tanhf_(e0.z + h0.z) * wl0.z + tanhf_(e0.w + h0.w) * wl0.w
                + tanhf_(e1.x + h1.x) * wl1.x + tanhf_(e1.y + h1.y) * wl1.y
                + tanhf_(e1.z + h1.z) * wl1.z + tanhf_(e1.w + h1.w) * wl1.w;
        #pragma unroll
        for (int msk = 16; msk >= 1; msk >>= 1) p += __shfl_xor(p, msk, 64);
        if (g == 0) scores[(size_t)(l0 + li) * BB + b0 + r] = p;
    }
}

// ---------------------------------------------------------------------------
// Same, from bf16 ep rows (tiers 2/3). sstr/soff in u16 units.
// ---------------------------------------------------------------------------
__global__ __launch_bounds__(256) void scores_ep_b16(
    const u16* __restrict__ ep, const float* __restrict__ hp,
    const float* __restrict__ Wl, float* __restrict__ scores,
    int sstr, int soff)
{
    __shared__ float hp_s[8 * 256];
    const int b0  = blockIdx.x * 8;
    const int l0  = blockIdx.y * 20;
    const int tid = threadIdx.x;
    const int r   = tid >> 5;
    const int g   = tid & 31;

    for (int v = tid; v < 512; v += 256)
        ((float4*)hp_s)[v] = ((const float4*)(hp + (size_t)b0 * 256))[v];
    __syncthreads();

    const float4 wl0 = *(const float4*)&Wl[g * 4];
    const float4 wl1 = *(const float4*)&Wl[128 + g * 4];
    const float4 h0  = *(const float4*)&hp_s[r * 256 + g * 4];
    const float4 h1  = *(const float4*)&hp_s[r * 256 + 128 + g * 4];

    #pragma unroll 2
    for (int li = 0; li < 20; ++li) {
        const u16* er = ep + ((size_t)(l0 + li) * BB + b0 + r) * sstr + soff;
        ushort4 u0 = *(const ushort4*)&er[g * 4];
        ushort4 u1 = *(const ushort4*)&er[128 + g * 4];
        float p = tanhf_(b2f_(u0.x) + h0.x) * wl0.x + tanhf_(b2f_(u0.y) + h0.y) * wl0.y
                + tanhf_(b2f_(u0.z) + h0.z) * wl0.z + tanhf_(b2f_(u0.w) + h0.w) * wl0.w
                + tanhf_(b2f_(u1.x) + h1.x) * wl1.x + tanhf_(b2f_(u1.y) + h1.y) * wl1.y
                + tanhf_(b2f_(u1.z) + h1.z) * wl1.z + tanhf_(b2f_(u1.w) + h1.w) * wl1.w;
        #pragma unroll
        for (int msk = 16; msk >= 1; msk >>= 1) p += __shfl_xor(p, msk, 64);
        if (g == 0) scores[(size_t)(l0 + li) * BB + b0 + r] = p;
    }
}

// ---------------------------------------------------------------------------
// softmax over L + ctx. fp32 enc variant (tiers 1/2). Block = 8 rows.
// ---------------------------------------------------------------------------
__global__ __launch_bounds__(256) void softmax_ctx(
    const float* __restrict__ scores, const float* __restrict__ enc_out,
    float* __restrict__ ctx)
{
    __shared__ float al_s[8 * 100];
    const int b0  = blockIdx.x * 8;
    const int tid = threadIdx.x;
    for (int v = tid; v < 800; v += 256) {
        int r = v / 100, l = v - r * 100;
        al_s[r * 100 + l] = scores[(size_t)l * BB + b0 + r];
    }
    __syncthreads();
    if (tid < 8) {
        float m = -1e30f;
        for (int l = 0; l < LL; ++l) m = fmaxf(m, al_s[tid * 100 + l]);
        float s = 0.f;
        for (int l = 0; l < LL; ++l) { float e = expf(al_s[tid * 100 + l] - m); al_s[tid * 100 + l] = e; s += e; }
        float inv = 1.f / s;
        for (int l = 0; l < LL; ++l) al_s[tid * 100 + l] *= inv;
    }
    __syncthreads();
    float acc[8] = {};
    for (int l = 0; l < LL; ++l) {
        const float* er = enc_out + (size_t)l * (BB * 256) + (size_t)b0 * 256 + tid;
        #pragma unroll
        for (int r = 0; r < 8; ++r) acc[r] += al_s[r * 100 + l] * er[r * 256];
    }
    for (int r = 0; r < 8; ++r) ctx[(size_t)(b0 + r) * 256 + tid] = acc[r];
}

// ---------------------------------------------------------------------------
// softmax over L + ctx, bf16 packed enc (tier 3).
// ---------------------------------------------------------------------------
__global__ __launch_bounds__(256) void softmax_ctx_b16(
    const float* __restrict__ scores, const u16* __restrict__ encp,
    float* __restrict__ ctx)
{
    __shared__ float al_s[8 * 100];
    const int b0  = blockIdx.x * 8;
    const int tid = threadIdx.x;
    for (int v = tid; v < 800; v += 256) {
        int r = v / 100, l = v - r * 100;
        al_s[r * 100 + l] = scores[(size_t)l * BB + b0 + r];
    }
    __syncthreads();
    if (tid < 8) {
        float m = -1e30f;
        for (int l = 0; l < LL; ++l) m = fmaxf(m, al_s[tid * 100 + l]);
        float s = 0.f;
        for (int l = 0; l < LL; ++l) { float e = expf(al_s[tid * 100 + l] - m); al_s[tid * 100 + l] = e; s += e; }
        float inv = 1.f / s;
        for (int l = 0; l < LL; ++l) al_s[tid * 100 + l] *= inv;
    }
    __syncthreads();
    float acc[8] = {};
    for (int l = 0; l < LL; ++l) {
        const u16* er = encp + ((size_t)l * BB + b0) * 512 + tid;
        #pragma unroll
        for (int r = 0; r < 8; ++r) acc[r] += al_s[r * 100 + l] * b2f_(er[r * 512]);
    }
    for (int r = 0; r < 8; ++r) ctx[(size_t)(b0 + r) * 256 + tid] = acc[r];
}

// ---------------------------------------------------------------------------
// Decoder LSTM cell: grid 256 x 512, block = 8 rows, half0 = ctx@Wdi,
// half1 = hd@Wdh, coalesced float4 weights. hd updated in place.
// ---------------------------------------------------------------------------
__global__ __launch_bounds__(512) void dec_step(
    const float* __restrict__ ctxp,
    const float* __restrict__ Wdi, const float* __restrict__ Wdh,
    const float* __restrict__ bdec,
    float* __restrict__ hd, float* __restrict__ c_st, int first)
{
    __shared__ float ct_s[8 * 256];        // 8 KB
    __shared__ float hd_s[8 * 256];        // 8 KB
    __shared__ float gate_s[2][8 * 1024];  // 64 KB
    const int row0 = blockIdx.x * 8;
    const int tid  = threadIdx.x;
    const int lane = tid & 63, w = tid >> 6;
    const int half = tid >> 8;
    const int ct   = tid & 255;
    const int c0   = ct * 4;

    ((float4*)ct_s)[tid] = ((const float4*)(ctxp + (size_t)row0 * 256))[tid];
    if (!first)
        ((float4*)hd_s)[tid] = ((const float4*)(hd + (size_t)row0 * 256))[tid];
    __syncthreads();

    float4 acc[8];
    {
        float4 b4 = *(const float4*)&bdec[c0];
        float4 bias4 = (half == 0) ? b4 : make_float4(0.f, 0.f, 0.f, 0.f);
        #pragma unroll
        for (int r = 0; r < 8; ++r) acc[r] = bias4;
    }
    if (half == 0) {
        const float* wP = Wdi + c0;
        #pragma unroll 2
        for (int ch = 0; ch < 64; ++ch) {
            const int k0 = ch * 4;
            float4 w0 = *(const float4*)&wP[(size_t)(k0 + 0) * 1024];
            float4 w1 = *(const float4*)&wP[(size_t)(k0 + 1) * 1024];
            float4 w2 = *(const float4*)&wP[(size_t)(k0 + 2) * 1024];
            float4 w3 = *(const float4*)&wP[(size_t)(k0 + 3) * 1024];
            #pragma unroll
            for (int r = 0; r < 8; ++r) {
                float4 av = *(const float4*)&ct_s[r * 256 + k0];
                acc[r].x += av.x * w0.x; acc[r].y += av.x * w0.y;
                acc[r].z += av.x * w0.z; acc[r].w += av.x * w0.w;
                acc[r].x += av.y * w1.x; acc[r].y += av.y * w1.y;
                acc[r].z += av.y * w1.z; acc[r].w += av.y * w1.w;
                acc[r].x += av.z * w2.x; acc[r].y += av.z * w2.y;
                acc[r].z += av.z * w2.z; acc[r].w += av.z * w2.w;
                acc[r].x += av.w * w3.x; acc[r].y += av.w * w3.y;
                acc[r].z += av.w * w3.z; acc[r].w += av.w * w3.w;
            }
        }
    } else if (!first) {
        const float* wP = Wdh + c0;
        #pragma unroll 2
        for (int ch = 0; ch < 64; ++ch) {
            const int k0 = ch * 4;
            float4 w0 = *(const float4*)&wP[(size_t)(k0 + 0) * 1024];
            float4 w1 = *(const float4*)&wP[(size_t)(k0 + 1) * 1024];
            float4 w2 = *(const float4*)&wP[(size_t)(k0 + 2) * 1024];
            float4 w3 = *(const float4*)&wP[(size_t)(k0 + 3) * 1024];
            #pragma unroll
            for (int r = 0; r < 8; ++r) {
                float4 av = *(const float4*)&hd_s[r * 256 + k0];
                acc[r].x += av.x * w0.x; acc[r].y += av.x * w0.y;
                acc[r].z += av.x * w0.z; acc[r].w += av.x * w0.w;
                acc[r].x += av.y * w1.x; acc[r].y += av.y * w1.y;
                acc[r].z += av.y * w1.z; acc[r].w += av.y * w1.w;
                acc[r].x += av.z * w2.x; acc[r].y += av.z * w2.y;
                acc[r].z += av.z * w2.z; acc[r].w += av.z * w2.w;
                acc[r].x += av.w * w3.x; acc[r].y += av.w * w3.y;
                acc[r].z += av.w * w3.z; acc[r].w += av.w * w3.w;
            }
        }
    }
    #pragma unroll
    for (int r = 0; r < 8; ++r)
        *(float4*)&gate_s[half][r * 1024 + c0] = acc[r];
    __syncthreads();

    {
        const float* g0 = &gate_s[0][w * 1024 + lane * 4];
        const float* g1 = &gate_s[1][w * 1024 + lane * 4];
        float4 giA = *(const float4*)&g0[0],   giB = *(const float4*)&g1[0];
        float4 gfA = *(const float4*)&g0[256], gfB = *(const float4*)&g1[256];
        float4 ggA = *(const float4*)&g0[512], ggB = *(const float4*)&g1[512];
        float4 goA = *(const float4*)&g0[768], goB = *(const float4*)&g1[768];
        size_t ci = (size_t)(row0 + w) * 256 + lane * 4;
        float4 c4 = first ? make_float4(0.f, 0.f, 0.f, 0.f)
                          : *(const float4*)&c_st[ci];
        float cc[4] = { c4.x, c4.y, c4.z, c4.w };
        float gi[4] = { giA.x + giB.x, giA.y + giB.y, giA.z + giB.z, giA.w + giB.w };
        float gf[4] = { gfA.x + gfB.x, gfA.y + gfB.y, gfA.z + gfB.z, gfA.w + gfB.w };
        float gg[4] = { ggA.x + ggB.x, ggA.y + ggB.y, ggA.z + ggB.z, ggA.w + ggB.w };
        float go[4] = { goA.x + goB.x, goA.y + goB.y, goA.z + goB.z, goA.w + goB.w };
        float4 cn, hn;
        #pragma unroll
        for (int uu = 0; uu < 4; ++uu) {
            float cv = sigmoidf_(gf[uu]) * cc[uu] + sigmoidf_(gi[uu]) * tanhf_(gg[uu]);
            float hv = sigmoidf_(go[uu]) * tanhf_(cv);
            if (uu == 0) { cn.x = cv; hn.x = hv; } else if (uu == 1) { cn.y = cv; hn.y = hv; }
            else if (uu == 2) { cn.z = cv; hn.z = hv; } else { cn.w = cv; hn.w = hv; }
        }
        *(float4*)&c_st[ci] = cn;
        *(float4*)&hd[ci]   = hn;
    }
}

// ---------------------------------------------------------------------------
// Head: fc = tanh(h_d@Wf+bf); out[:,step] = tanh(fc@Wo+bo). Block = 16 rows.
// ---------------------------------------------------------------------------
__global__ __launch_bounds__(256) void head_k(
    const float* __restrict__ hd, const float* __restrict__ Wf,
    const float* __restrict__ bf, const float* __restrict__ Wo,
    const float* __restrict__ bo, float* __restrict__ out, int step)
{
    __shared__ float hd_s[16 * 256];
    __shared__ float fc_s[16 * 128];
    const int b0  = blockIdx.x * 16;
    const int tid = threadIdx.x;
    {
        const float4* hg = (const float4*)(hd + (size_t)b0 * 256);
        for (int i = tid; i < 1024; i += 256) ((float4*)hd_s)[i] = hg[i];
    }
    __syncthreads();
    {
        const int f = tid & 127, rg = tid >> 7;
        float acc[8];
        float bfv = bf[f];
        #pragma unroll
        for (int rr = 0; rr < 8; ++rr) acc[rr] = bfv;
        const float* wp = Wf + f;
        #pragma unroll 2
        for (int k = 0; k < 256; ++k) {
            float wv = wp[k * 128];
            #pragma unroll
            for (int rr = 0; rr < 8; ++rr) acc[rr] += hd_s[(rg * 8 + rr) * 256 + k] * wv;
        }
        for (int rr = 0; rr < 8; ++rr) fc_s[(rg * 8 + rr) * 128 + f] = tanhf_(acc[rr]);
    }
    __syncthreads();
    {
        const int lane = tid & 63, w = tid >> 6;
        const float bov = bo[0];
        #pragma unroll
        for (int rr = 0; rr < 4; ++rr) {
            int r = w * 4 + rr;
            float p = fc_s[r * 128 + lane] * Wo[lane] + fc_s[r * 128 + 64 + lane] * Wo[64 + lane];
            #pragma unroll
            for (int msk = 32; msk >= 1; msk >>= 1) p += __shfl_xor(p, msk, 64);
            if (lane == 0) out[(size_t)(b0 + r) * NOUT + step] = tanhf_(p + bov);
        }
    }
}

extern "C" void kernel_launch(void* const* d_in, const int* in_sizes, int n_in,
                              void* d_out, int out_size, void* d_ws, size_t ws_size,
                              hipStream_t stream)
{
    const float* x    = (const float*)d_in[0];
    const float* Wa   = (const float*)d_in[1];
    const float* ba   = (const float*)d_in[2];
    const float* Wi   = (const float*)d_in[3];
    const float* Wh   = (const float*)d_in[4];
    const float* be   = (const float*)d_in[5];
    const float* Wd   = (const float*)d_in[6];
    const float* bd   = (const float*)d_in[7];
    const float* Wl   = (const float*)d_in[8];
    const float* bl   = (const float*)d_in[9];
    const float* Wdi  = (const float*)d_in[10];
    const float* Wdh  = (const float*)d_in[11];
    const float* bdec = (const float*)d_in[12];
    const float* Wf   = (const float*)d_in[13];
    const float* bf   = (const float*)d_in[14];
    const float* Wo   = (const float*)d_in[15];
    const float* bo   = (const float*)d_in[16];
    float* out = (float*)d_out;

    // ws layout (floats): enc_out(/packed) | hd | c_d | ctx(=hp=wprep alias) | scores | [ep]
    const size_t f_enc    = (size_t)LL * BB * EE;     // 52,428,800
    const size_t f_state  = (size_t)BB * EE;          // 524,288
    const size_t f_scores = (size_t)LL * BB;          // 204,800
    const size_t need3 = (f_enc + 3 * f_state + f_scores) * sizeof(float);
    const size_t need2 = need3 + f_enc * sizeof(u16);
    const size_t need1 = need3 + f_enc * sizeof(float);

    float* ws      = (float*)d_ws;
    float* enc_out = ws;
    float* hd      = enc_out + f_enc;
    float* c_d     = hd + f_state;
    float* ctx     = c_d + f_state;      // also hp AND the encoder weight-prep
    float* scores  = ctx + f_state;      //   buffer (disjoint lifetimes)
    float* ep32    = scores + f_scores;  // tier 1 only
    u16*   ep16    = (u16*)(scores + f_scores);  // tier 2 only
    float* hp      = ctx;
    u16*   wprep   = (u16*)ctx;          // 680 tiles x 1024 u16 = 1.36 MB <= 2 MB

    if (ws_size < need3) return;   // diagnostic clean-fail (known satisfied)
    const int tier = (ws_size >= need1) ? 1 : (ws_size >= need2) ? 2 : 3;

    // encoder weights -> bf16 hi/lo MFMA fragments (ctx region is dead here)
    w_prep<<<680, 64, 0, stream>>>(Wi, Wh, Wa, wprep);
    // persistent MFMA encoder: 64 blocks x 1024 threads, 32 rows/block
    enc_mfma<<<64, 1024, 0, stream>>>(x, ba, be, wprep, enc_out);

    // hoist the step-invariant enc_out @ Wd_top out of the decode loop
    if (tier == 1)
        gemm_nk256<<<(LL * BB) / 32, 256, 0, stream>>>(
            enc_out, Wd, (const float*)nullptr, ep32, 0);
    else
        pack_ep<<<(LL * BB) / 32, 256, 0, stream>>>(
            enc_out, Wd, ep16, tier == 3 ? 1 : 0);

    for (int s = 0; s < NOUT; ++s) {
        // hp = hd @ Wd_bot + bd  (step 0: hd == 0 -> hp = bd)
        gemm_nk256<<<BB / 32, 256, 0, stream>>>(
            hd, Wd + 256 * 256, bd, hp, s == 0);
        if (tier == 1)
            scores_ep_f32<<<dim3(BB / 8, 5), 256, 0, stream>>>(ep32, hp, Wl, scores);
        else if (tier == 2)
            scores_ep_b16<<<dim3(BB / 8, 5), 256, 0, stream>>>(ep16, hp, Wl, scores, 256, 0);
        else
            scores_ep_b16<<<dim3(BB / 8, 5), 256, 0, stream>>>(
                (const u16*)enc_out, hp, Wl, scores, 512, 256);
        if (tier == 3)
            softmax_ctx_b16<<<BB / 8, 256, 0, stream>>>(scores, (const u16*)enc_out, ctx);
        else
            softmax_ctx<<<BB / 8, 256, 0, stream>>>(scores, enc_out, ctx);
        dec_step<<<BB / 8, 512, 0, stream>>>(ctx, Wdi, Wdh, bdec, hd, c_d, s == 0);
        head_k<<<BB / 16, 256, 0, stream>>>(hd, Wf, bf, Wo, bo, out, s);
    }
}

// Round 4
// 2381.551 us; speedup vs baseline: 1.8650x; 1.1977x over previous
//
#include <hip/hip_runtime.h>
#include <math.h>

// Problem constants
#define BB 2048
#define LL 100
#define FF 64
#define EE 256
#define DD 256
#define NOUT 3

#define COMP(v, i) ((i) == 0 ? (v).x : (i) == 1 ? (v).y : (i) == 2 ? (v).z : (v).w)

typedef unsigned short u16;
typedef unsigned int u32;
typedef __attribute__((ext_vector_type(8))) __bf16 bf16x8;
typedef __attribute__((ext_vector_type(4))) float f32x4;
typedef __attribute__((ext_vector_type(2))) float f32x2;

#define MFMA_(A, B, C) __builtin_amdgcn_mfma_f32_16x16x32_bf16((A), (B), (C), 0, 0, 0)

__device__ __forceinline__ float sigmoidf_(float x) {
    return 1.0f / (1.0f + expf(-x));
}
// tanh via identity 1 - 2/(1+e^{2x}); ~2e-7 abs fp32 error, saturates correctly.
__device__ __forceinline__ float tanhf_(float x) {
    return 1.0f - 2.0f / (1.0f + expf(2.0f * x));
}
// fp32 -> bf16 round-to-nearest-even
__device__ __forceinline__ u16 f2b_(float f) {
    u32 u = __float_as_uint(f);
    u = (u + 0x7FFFu + ((u >> 16) & 1u)) >> 16;
    return (u16)u;
}
__device__ __forceinline__ float b2f_(u16 b) {
    return __uint_as_float(((u32)b) << 16);
}
__device__ __forceinline__ u32 pack2_(float a, float b) {
    return (u32)f2b_(a) | ((u32)f2b_(b) << 16);
}
__device__ __forceinline__ f32x4 splat4(float b) {
    f32x4 v; v[0] = b; v[1] = b; v[2] = b; v[3] = b; return v;
}
// split 8 fp32 into bf16 hi/lo planes packed as uint4 (little-endian pairs)
__device__ __forceinline__ void split8(const float* v, uint4& H, uint4& L) {
    u16 h[8], lo[8];
    #pragma unroll
    for (int e = 0; e < 8; ++e) {
        h[e]  = f2b_(v[e]);
        lo[e] = f2b_(v[e] - b2f_(h[e]));
    }
    H = make_uint4((u32)h[0]  | ((u32)h[1]  << 16), (u32)h[2]  | ((u32)h[3]  << 16),
                   (u32)h[4]  | ((u32)h[5]  << 16), (u32)h[6]  | ((u32)h[7]  << 16));
    L = make_uint4((u32)lo[0] | ((u32)lo[1] << 16), (u32)lo[2] | ((u32)lo[3] << 16),
                   (u32)lo[4] | ((u32)lo[5] << 16), (u32)lo[6] | ((u32)lo[7] << 16));
}

// A-fragment LDS index: [mt][kt][plane][lane][8] u16
#define AF(mt, kt, p, ln) (((((mt) * 10 + (kt)) * 2 + (p)) * 64 + (ln)) * 8)

// ---------------------------------------------------------------------------
// Weight prep (once per launch, ~1.36 MB into the dead ctx region):
// bf16 hi/lo split of [Wi;Wh] (tiles 0..639) and Wa (tiles 640..679) in MFMA
// B-fragment order. Tile (nt,kt) = 1024 u16: plane-hi [64 lanes][8 e], then lo.
// Element (lane l, e) = W[k = kt*32 + (l>>4)*8 + e][col = nt*16 + (l&15)].
// ---------------------------------------------------------------------------
__global__ __launch_bounds__(64) void w_prep(
    const float* __restrict__ Wi, const float* __restrict__ Wh,
    const float* __restrict__ Wa, u16* __restrict__ wp)
{
    const int bid = blockIdx.x;      // 0..679
    const int l   = threadIdx.x;     // 0..63
    const int isA = (bid >= 640);
    const int b2  = isA ? bid - 640 : bid;
    const int nt  = b2 / 10, kt = b2 - nt * 10;
    const int col = nt * 16 + (l & 15);

    float v[8];
    #pragma unroll
    for (int e = 0; e < 8; ++e) {
        const int k = kt * 32 + ((l >> 4) << 3) + e;
        v[e] = isA ? Wa[(size_t)k * 64 + col]
                   : (k < 64 ? Wi[(size_t)k * 1024 + col]
                             : Wh[(size_t)(k - 64) * 1024 + col]);
    }
    uint4 H, L;
    split8(v, H, L);
    *(uint4*)&wp[(size_t)bid * 1024 + (size_t)l * 8]       = H;
    *(uint4*)&wp[(size_t)bid * 1024 + 512 + (size_t)l * 8] = L;
}

// ---------------------------------------------------------------------------
// Persistent MFMA encoder, weight-register-stationary 4-way N-split.
// Grid 256 x 1024 (1 block/CU, all co-resident: 89 KB LDS forces 1/CU and
// grid == CU count). Block (g = group 0..63, p = unit-quarter 0..3):
// rows g*32..+32, gate units p*64..+64 -> 16 N-tiles; wave w owns N-tile
// nt = (w>>2)*16 + p*4 + (w&3), with its B-hi plane (10 uint4 = 40 VGPR)
// register-resident for the entire kernel. B-lo + Wa stream from warm L2.
// h-slices are exchanged between the 4 partner blocks of a group through a
// double-buffered global hbuf using sc0/sc1 (coherence-point) accesses and a
// per-group monotonic atomic counter; bounded spin (no hang possible).
// XCD swizzle puts the 4 partners on one XCD (perf heuristic only).
// ---------------------------------------------------------------------------
__global__ __launch_bounds__(1024) void enc_mfma4(
    const float* __restrict__ x,
    const float* __restrict__ ba, const float* __restrict__ be,
    const u16* __restrict__ wp,
    float* __restrict__ enc_out,
    float* __restrict__ hbuf,          // [2][BB][256] fp32 (aliases hd|c_d)
    u32* __restrict__ flags)           // [64] monotonic counters (memset 0)
{
    __shared__ u16   aFrag[20480];         // 40 KB A-fragments (bf16 hi/lo)
    __shared__ float x_s[32 * 68];         // 8.5 KB x fp32
    __shared__ float e_s[32 * 68];         // 8.5 KB attention energies
    __shared__ float gate_s[4][32][64];    // 32 KB gate pre-activations

    const int bid = blockIdx.x;
    const int g   = (bid & 7) | ((bid >> 5) << 3);   // group 0..63
    const int p   = (bid >> 3) & 3;                  // unit-quarter (ug)
    const int row0 = g * 32;
    const int tid = threadIdx.x;
    const int l   = tid & 63;
    const int w   = tid >> 6;                        // wave 0..15

    // zero aFrag (h region must be 0 at t=0)
    for (int v = tid; v < 20480 / 2; v += 1024) ((u32*)aFrag)[v] = 0u;

    // per-wave N-tile and register-resident B-hi plane
    const int ntW = (w >> 2) * 16 + p * 4 + (w & 3);
    uint4 BhR[10];
    #pragma unroll
    for (int kt = 0; kt < 10; ++kt)
        BhR[kt] = *(const uint4*)&wp[(size_t)(ntW * 10 + kt) * 1024 + (size_t)l * 8];

    const float be_r = be[(size_t)ntW * 16 + (l & 15)];
    const float ba_r = (w < 8) ? ba[(w & 3) * 16 + (l & 15)] : 0.f;

    float c_state[2] = {0.f, 0.f};     // epilogue cells: (row=tid>>5, units 2q,2q+1)

    __syncthreads();

    for (int t = 0; t < LL; ++t) {
        // ---- S1: wait for all 4 partner blocks to finish t-1 ----
        if (t > 0) {
            if (tid == 0) {
                const u32 target = 4u * (u32)t;
                int guard = 0;
                while (__hip_atomic_load(&flags[g], __ATOMIC_RELAXED,
                                         __HIP_MEMORY_SCOPE_AGENT) < target) {
                    __builtin_amdgcn_s_sleep(1);
                    if (++guard > 2000000) break;   // bounded: no GPU hang
                }
            }
            __syncthreads();
        }

        // ---- P0: stage x_t frags (tid<256) | partner-h frags (tid>=256) ----
        if (tid < 256) {
            const int kt2 = tid >> 7;          // 0..1
            const int mt  = (tid >> 6) & 1;    // 0..1
            const int l2  = tid & 63;
            const int row2 = mt * 16 + (l2 & 15);
            const int f0   = kt2 * 32 + ((l2 >> 4) << 3);
            const float* xp = x + (size_t)(row0 + row2) * (LL * FF) + (size_t)t * FF + f0;
            float4 xa = *(const float4*)xp;
            float4 xb = *(const float4*)(xp + 4);
            float v[8] = {xa.x, xa.y, xa.z, xa.w, xb.x, xb.y, xb.z, xb.w};
            uint4 H, L;
            split8(v, H, L);
            *(uint4*)&aFrag[AF(mt, kt2, 0, l2)] = H;
            *(uint4*)&aFrag[AF(mt, kt2, 1, l2)] = L;
            *(float4*)&x_s[row2 * 68 + f0]     = xa;
            *(float4*)&x_s[row2 * 68 + f0 + 4] = xb;
        } else if (t > 0) {
            const int v   = tid - 256;         // 0..767
            const int prl = v >> 8;            // 0..2 (relative partner)
            const int vv  = v & 255;
            const int row = vv >> 3;           // 0..31
            const int i8  = vv & 7;            // 8-unit chunk
            const int ugp = (p + 1 + prl) & 3;
            const int u8  = ugp * 64 + i8 * 8; // global unit base (mult of 8)
            const float* hp_g = hbuf + ((size_t)((t - 1) & 1) * BB + row0 + row) * 256 + u8;
            f32x4 a4, b4;
            asm volatile("global_load_dwordx4 %0, %2, off sc0 sc1\n\t"
                         "global_load_dwordx4 %1, %3, off sc0 sc1\n\t"
                         "s_waitcnt vmcnt(0)"
                         : "=v"(a4), "=v"(b4)
                         : "v"(hp_g), "v"(hp_g + 4) : "memory");
            float v8[8] = {a4[0], a4[1], a4[2], a4[3], b4[0], b4[1], b4[2], b4[3]};
            uint4 H, L;
            split8(v8, H, L);
            const int mt = row >> 4, rowT = row & 15;
            const int kt_h = 2 + (u8 >> 5);
            const int g2   = (u8 & 31) >> 3;
            const int ln   = rowT + (g2 << 4);
            *(uint4*)&aFrag[AF(mt, kt_h, 0, ln)] = H;
            *(uint4*)&aFrag[AF(mt, kt_h, 1, ln)] = L;
        }
        __syncthreads();   // A: x/h fragments visible

        // ---- P1: attention energies (waves 0..7: mt = w>>2, nta = w&3) ----
        if (w < 8) {
            const int mt  = w >> 2;
            const int nta = w & 3;
            f32x4 ea = splat4(ba_r);
            #pragma unroll
            for (int kt = 0; kt < 10; ++kt) {
                bf16x8 Ah = *(const bf16x8*)&aFrag[AF(mt, kt, 0, l)];
                bf16x8 Al = *(const bf16x8*)&aFrag[AF(mt, kt, 1, l)];
                const size_t o = (size_t)(640 + nta * 10 + kt) * 1024 + (size_t)l * 8;
                bf16x8 Bh = *(const bf16x8*)&wp[o];
                bf16x8 Bl = *(const bf16x8*)&wp[o + 512];
                ea = MFMA_(Ah, Bh, ea);
                ea = MFMA_(Al, Bh, ea);
                ea = MFMA_(Ah, Bl, ea);
            }
            const int colA = nta * 16 + (l & 15);
            #pragma unroll
            for (int r = 0; r < 4; ++r) {
                const int rowT = ((l >> 4) << 2) + r;
                e_s[(mt * 16 + rowT) * 68 + colA] = tanhf_(ea[r]);
            }
        }
        __syncthreads();   // B: energies staged

        // ---- P2: softmax over 64 cols + ein fragments (tid<512) ----
        if (tid < 512) {
            const int row2 = tid >> 4;           // 0..31
            const int c4   = (tid & 15) * 4;     // 0..60
            float4 ev = *(const float4*)&e_s[row2 * 68 + c4];
            float m = fmaxf(fmaxf(ev.x, ev.y), fmaxf(ev.z, ev.w));
            #pragma unroll
            for (int msk = 8; msk >= 1; msk >>= 1) m = fmaxf(m, __shfl_xor(m, msk, 64));
            float4 ex;
            ex.x = expf(ev.x - m); ex.y = expf(ev.y - m);
            ex.z = expf(ev.z - m); ex.w = expf(ev.w - m);
            float s = ex.x + ex.y + ex.z + ex.w;
            #pragma unroll
            for (int msk = 8; msk >= 1; msk >>= 1) s += __shfl_xor(s, msk, 64);
            const float inv = 1.f / s;
            float4 xv = *(const float4*)&x_s[row2 * 68 + c4];
            float ein[4] = { ex.x * inv * xv.x, ex.y * inv * xv.y,
                             ex.z * inv * xv.z, ex.w * inv * xv.w };
            const int mt   = row2 >> 4;
            const int rowT = row2 & 15;
            const int kt   = c4 >> 5;
            const int g2   = (c4 & 31) >> 3;
            const int e0   = c4 & 7;             // 0 or 4
            const int ln   = rowT + (g2 << 4);
            ushort4 h4, l4;
            #pragma unroll
            for (int e = 0; e < 4; ++e) {
                u16 hh = f2b_(ein[e]);
                u16 ll = f2b_(ein[e] - b2f_(hh));
                if (e == 0) { h4.x = hh; l4.x = ll; } else if (e == 1) { h4.y = hh; l4.y = ll; }
                else if (e == 2) { h4.z = hh; l4.z = ll; } else { h4.w = hh; l4.w = ll; }
            }
            *(ushort4*)&aFrag[AF(mt, kt, 0, ln) + e0] = h4;
            *(ushort4*)&aFrag[AF(mt, kt, 1, ln) + e0] = l4;
        }
        __syncthreads();   // C: ein fragments staged

        // ---- P3: gate GEMM, B-hi from registers, B-lo streamed (L2) ----
        f32x4 acc0 = splat4(be_r), acc1 = splat4(be_r);
        #pragma unroll
        for (int kt = 0; kt < 10; ++kt) {
            bf16x8 Ah0 = *(const bf16x8*)&aFrag[AF(0, kt, 0, l)];
            bf16x8 Al0 = *(const bf16x8*)&aFrag[AF(0, kt, 1, l)];
            bf16x8 Ah1 = *(const bf16x8*)&aFrag[AF(1, kt, 0, l)];
            bf16x8 Al1 = *(const bf16x8*)&aFrag[AF(1, kt, 1, l)];
            bf16x8 Bl  = *(const bf16x8*)&wp[(size_t)(ntW * 10 + kt) * 1024 + 512 + (size_t)l * 8];
            bf16x8 Bh  = __builtin_bit_cast(bf16x8, BhR[kt]);
            acc0 = MFMA_(Ah0, Bh, acc0);
            acc1 = MFMA_(Ah1, Bh, acc1);
            acc0 = MFMA_(Al0, Bh, acc0);
            acc1 = MFMA_(Al1, Bh, acc1);
            acc0 = MFMA_(Ah0, Bl, acc0);
            acc1 = MFMA_(Ah1, Bl, acc1);
        }
        // stage gates: gate = w>>2, unit_local = (w&3)*16 + (l&15)
        {
            const int gate = w >> 2;
            const int ulb  = (w & 3) * 16 + (l & 15);
            #pragma unroll
            for (int r = 0; r < 4; ++r) {
                const int rT = ((l >> 4) << 2) + r;
                gate_s[gate][rT][ulb]      = acc0[r];
                gate_s[gate][16 + rT][ulb] = acc1[r];
            }
        }
        __syncthreads();   // D: gates staged; aFrag reads done

        // ---- epilogue: 1024 threads x 2 cells; h out + own h-frags ----
        {
            const int row = tid >> 5;            // 0..31
            const int q2  = (tid & 31) * 2;      // unit_local 0..62 even
            float gi0 = gate_s[0][row][q2], gi1 = gate_s[0][row][q2 + 1];
            float gf0 = gate_s[1][row][q2], gf1 = gate_s[1][row][q2 + 1];
            float gg0 = gate_s[2][row][q2], gg1 = gate_s[2][row][q2 + 1];
            float go0 = gate_s[3][row][q2], go1 = gate_s[3][row][q2 + 1];
            float cv0 = sigmoidf_(gf0) * c_state[0] + sigmoidf_(gi0) * tanhf_(gg0);
            float cv1 = sigmoidf_(gf1) * c_state[1] + sigmoidf_(gi1) * tanhf_(gg1);
            c_state[0] = cv0; c_state[1] = cv1;
            float hv0 = sigmoidf_(go0) * tanhf_(cv0);
            float hv1 = sigmoidf_(go1) * tanhf_(cv1);
            const int u_g = p * 64 + q2;
            // enc_out (plain store)
            *(float2*)&enc_out[((size_t)t * BB + row0 + row) * 256 + u_g]
                = make_float2(hv0, hv1);
            // hbuf write-through (coherence point) for partner blocks
            float* hp_g = hbuf + ((size_t)(t & 1) * BB + row0 + row) * 256 + u_g;
            f32x2 hv2; hv2[0] = hv0; hv2[1] = hv1;
            asm volatile("global_store_dwordx2 %0, %1, off sc0 sc1"
                         :: "v"(hp_g), "v"(hv2) : "memory");
            // own h-fragments for t+1
            const int mt = row >> 4, rowT = row & 15;
            const int kt_h = 2 + (u_g >> 5);
            const int g2   = (u_g & 31) >> 3;
            const int ln   = rowT + (g2 << 4);
            const int e    = u_g & 7;            // even
            ((u32*)aFrag)[(AF(mt, kt_h, 0, ln) + e) >> 1] = pack2_(hv0, hv1);
            u16 h0 = f2b_(hv0), h1 = f2b_(hv1);
            ((u32*)aFrag)[(AF(mt, kt_h, 1, ln) + e) >> 1] =
                (u32)f2b_(hv0 - b2f_(h0)) | ((u32)f2b_(hv1 - b2f_(h1)) << 16);
        }
        asm volatile("s_waitcnt vmcnt(0)" ::: "memory");   // h stores complete
        __syncthreads();   // E: all waves' stores acked
        if (tid == 0)
            __hip_atomic_fetch_add(&flags[g], 1u, __ATOMIC_RELEASE,
                                   __HIP_MEMORY_SCOPE_AGENT);
    }
}

// ---------------------------------------------------------------------------
// Generic fp32 GEMM C(M,256) = A(M,256) @ W(256,256) [+ bias].
// Block = 32 rows, 256 threads. skip_gemm: C = bias (decoder step 0, hd==0).
// ---------------------------------------------------------------------------
__global__ __launch_bounds__(256) void gemm_nk256(
    const float* __restrict__ A, const float* __restrict__ W,
    const float* __restrict__ bias, float* __restrict__ C, int skip_gemm)
{
    __shared__ float a_s[32 * 256];   // 32 KB
    const int m0   = blockIdx.x * 32;
    const int tid  = threadIdx.x;
    const int lane = tid & 63;
    const int rg   = tid >> 6;        // 0..3 -> rows rg*8..rg*8+7
    const int n0   = lane * 4;

    float4 bias4 = make_float4(0.f, 0.f, 0.f, 0.f);
    if (bias) bias4 = *(const float4*)&bias[n0];

    if (skip_gemm) {
        #pragma unroll
        for (int r = 0; r < 8; ++r)
            *(float4*)&C[(size_t)(m0 + rg * 8 + r) * 256 + n0] = bias4;
        return;
    }

    for (int v = tid; v < 32 * 64; v += 256)
        ((float4*)a_s)[v] = ((const float4*)(A + (size_t)m0 * 256))[v];
    __syncthreads();

    float4 acc[8];
    #pragma unroll
    for (int r = 0; r < 8; ++r) acc[r] = bias4;

    #pragma unroll 2
    for (int k = 0; k < 256; k += 4) {
        float4 wv[4];
        #pragma unroll
        for (int kk = 0; kk < 4; ++kk)
            wv[kk] = *(const float4*)&W[(size_t)(k + kk) * 256 + n0];
        float4 av[8];
        #pragma unroll
        for (int r = 0; r < 8; ++r)
            av[r] = *(const float4*)&a_s[(rg * 8 + r) * 256 + k];
        #pragma unroll
        for (int kk = 0; kk < 4; ++kk) {
            #pragma unroll
            for (int r = 0; r < 8; ++r) {
                float e = COMP(av[r], kk);
                acc[r].x += e * wv[kk].x; acc[r].y += e * wv[kk].y;
                acc[r].z += e * wv[kk].z; acc[r].w += e * wv[kk].w;
            }
        }
    }
    #pragma unroll
    for (int r = 0; r < 8; ++r)
        *(float4*)&C[(size_t)(m0 + rg * 8 + r) * 256 + n0] = acc[r];
}

// ---------------------------------------------------------------------------
// ep = enc_out @ Wd_top, emitted as bf16 (tiers 2/3 fallback).
// ---------------------------------------------------------------------------
__global__ __launch_bounds__(256) void pack_ep(
    float* A, const float* __restrict__ W, u16* epOut, int packed)
{
    __shared__ float a_s[32 * 256];   // 32 KB
    const int m0   = blockIdx.x * 32;
    const int tid  = threadIdx.x;
    const int lane = tid & 63;
    const int rg   = tid >> 6;
    const int n0   = lane * 4;

    for (int v = tid; v < 32 * 64; v += 256)
        ((float4*)a_s)[v] = ((const float4*)(A + (size_t)m0 * 256))[v];
    __syncthreads();

    float4 acc[8];
    #pragma unroll
    for (int r = 0; r < 8; ++r) acc[r] = make_float4(0.f, 0.f, 0.f, 0.f);

    #pragma unroll 2
    for (int k = 0; k < 256; k += 4) {
        float4 wv[4];
        #pragma unroll
        for (int kk = 0; kk < 4; ++kk)
            wv[kk] = *(const float4*)&W[(size_t)(k + kk) * 256 + n0];
        float4 av[8];
        #pragma unroll
        for (int r = 0; r < 8; ++r)
            av[r] = *(const float4*)&a_s[(rg * 8 + r) * 256 + k];
        #pragma unroll
        for (int kk = 0; kk < 4; ++kk) {
            #pragma unroll
            for (int r = 0; r < 8; ++r) {
                float e = COMP(av[r], kk);
                acc[r].x += e * wv[kk].x; acc[r].y += e * wv[kk].y;
                acc[r].z += e * wv[kk].z; acc[r].w += e * wv[kk].w;
            }
        }
    }

    u16* epu = packed ? (u16*)A : epOut;
    #pragma unroll
    for (int r = 0; r < 8; ++r) {
        const size_t row = (size_t)(m0 + rg * 8 + r);
        ushort4 o;
        o.x = f2b_(acc[r].x); o.y = f2b_(acc[r].y);
        o.z = f2b_(acc[r].z); o.w = f2b_(acc[r].w);
        u16* dst = packed ? (epu + row * 512 + 256 + n0)
                          : (epu + row * 256 + n0);
        *(ushort4*)dst = o;
    }

    if (packed) {
        u32* ab = (u32*)A;
        for (int v = tid; v < 32 * 128; v += 256) {
            const int row = v >> 7, j = v & 127;
            float2 f = *(const float2*)&a_s[(row << 8) + (j << 1)];
            ab[((size_t)(m0 + row)) * 256 + j] = pack2_(f.x, f.y);
        }
    }
}

// ---------------------------------------------------------------------------
// Per-step decoder scores from precomputed fp32 ep (tier 1):
//   score[l,b] = Wl . tanh(ep[l,b,:] + hp[b,:])   (bl cancels in softmax)
// ---------------------------------------------------------------------------
__global__ __launch_bounds__(256) void scores_ep_f32(
    const float* __restrict__ ep, const float* __restrict__ hp,
    const float* __restrict__ Wl, float* __restrict__ scores)
{
    __shared__ float hp_s[8 * 256];
    const int b0  = blockIdx.x * 8;
    const int l0  = blockIdx.y * 20;
    const int tid = threadIdx.x;
    const int r   = tid >> 5;
    const int g   = tid & 31;

    for (int v = tid; v < 512; v += 256)
        ((float4*)hp_s)[v] = ((const float4*)(hp + (size_t)b0 * 256))[v];
    __syncthreads();

    const float4 wl0 = *(const float4*)&Wl[g * 4];
    const float4 wl1 = *(const float4*)&Wl[128 + g * 4];
    const float4 h0  = *(const float4*)&hp_s[r * 256 + g * 4];
    const float4 h1  = *(const float4*)&hp_s[r * 256 + 128 + g * 4];
    const float* eb  = ep + (size_t)l0 * (BB * 256) + (size_t)(b0 + r) * 256;

    #pragma unroll 2
    for (int li = 0; li < 20; ++li) {
        float4 e0 = *(const float4*)&eb[(size_t)li * (BB * 256) + g * 4];
        float4 e1 = *(const float4*)&eb[(size_t)li * (BB * 256) + 128 + g * 4];
        float p = tanhf_(e0.x + h0.x) * wl0.x + tanhf_(e0.y + h0.y) * wl0.y
                + tanhf_(e0.z + h0.z) * wl0.z + tanhf_(e0.w + h0.w) * wl0.w
                + tanhf_(e1.x + h1.x) * wl1.x + tanhf_(e1.y + h1.y) * wl1.y
                + tanhf_(e1.z + h1.z) * wl1.z + tanhf_(e1.w + h1.w) * wl1.w;
        #pragma unroll
        for (int msk = 16; msk >= 1; msk >>= 1) p += __shfl_xor(p, msk, 64);
        if (g == 0) scores[(size_t)(l0 + li) * BB + b0 + r] = p;
    }
}

// ---------------------------------------------------------------------------
// Same, from bf16 ep rows (tiers 2/3). sstr/soff in u16 units.
// ---------------------------------------------------------------------------
__global__ __launch_bounds__(256) void scores_ep_b16(
    const u16* __restrict__ ep, const float* __restrict__ hp,
    const float* __restrict__ Wl, float* __restrict__ scores,
    int sstr, int soff)
{
    __shared__ float hp_s[8 * 256];
    const int b0  = blockIdx.x * 8;
    const int l0  = blockIdx.y * 20;
    const int tid = threadIdx.x;
    const int r   = tid >> 5;
    const int g   = tid & 31;

    for (int v = tid; v < 512; v += 256)
        ((float4*)hp_s)[v] = ((const float4*)(hp + (size_t)b0 * 256))[v];
    __syncthreads();

    const float4 wl0 = *(const float4*)&Wl[g * 4];
    const float4 wl1 = *(const float4*)&Wl[128 + g * 4];
    const float4 h0  = *(const float4*)&hp_s[r * 256 + g * 4];
    const float4 h1  = *(const float4*)&hp_s[r * 256 + 128 + g * 4];

    #pragma unroll 2
    for (int li = 0; li < 20; ++li) {
        const u16* er = ep + ((size_t)(l0 + li) * BB + b0 + r) * sstr + soff;
        ushort4 u0 = *(const ushort4*)&er[g * 4];
        ushort4 u1 = *(const ushort4*)&er[128 + g * 4];
        float p = tanhf_(b2f_(u0.x) + h0.x) * wl0.x + tanhf_(b2f_(u0.y) + h0.y) * wl0.y
                + tanhf_(b2f_(u0.z) + h0.z) * wl0.z + tanhf_(b2f_(u0.w) + h0.w) * wl0.w
                + tanhf_(b2f_(u1.x) + h1.x) * wl1.x + tanhf_(b2f_(u1.y) + h1.y) * wl1.y
                + tanhf_(b2f_(u1.z) + h1.z) * wl1.z + tanhf_(b2f_(u1.w) + h1.w) * wl1.w;
        #pragma unroll
        for (int msk = 16; msk >= 1; msk >>= 1) p += __shfl_xor(p, msk, 64);
        if (g == 0) scores[(size_t)(l0 + li) * BB + b0 + r] = p;
    }
}

// ---------------------------------------------------------------------------
// softmax over L + ctx. fp32 enc variant (tiers 1/2). Block = 8 rows.
// ---------------------------------------------------------------------------
__global__ __launch_bounds__(256) void softmax_ctx(
    const float* __restrict__ scores, const float* __restrict__ enc_out,
    float* __restrict__ ctx)
{
    __shared__ float al_s[8 * 100];
    const int b0  = blockIdx.x * 8;
    const int tid = threadIdx.x;
    for (int v = tid; v < 800; v += 256) {
        int r = v / 100, l = v - r * 100;
        al_s[r * 100 + l] = scores[(size_t)l * BB + b0 + r];
    }
    __syncthreads();
    if (tid < 8) {
        float m = -1e30f;
        for (int l = 0; l < LL; ++l) m = fmaxf(m, al_s[tid * 100 + l]);
        float s = 0.f;
        for (int l = 0; l < LL; ++l) { float e = expf(al_s[tid * 100 + l] - m); al_s[tid * 100 + l] = e; s += e; }
        float inv = 1.f / s;
        for (int l = 0; l < LL; ++l) al_s[tid * 100 + l] *= inv;
    }
    __syncthreads();
    float acc[8] = {};
    for (int l = 0; l < LL; ++l) {
        const float* er = enc_out + (size_t)l * (BB * 256) + (size_t)b0 * 256 + tid;
        #pragma unroll
        for (int r = 0; r < 8; ++r) acc[r] += al_s[r * 100 + l] * er[r * 256];
    }
    for (int r = 0; r < 8; ++r) ctx[(size_t)(b0 + r) * 256 + tid] = acc[r];
}

// ---------------------------------------------------------------------------
// softmax over L + ctx, bf16 packed enc (tier 3).
// ---------------------------------------------------------------------------
__global__ __launch_bounds__(256) void softmax_ctx_b16(
    const float* __restrict__ scores, const u16* __restrict__ encp,
    float* __restrict__ ctx)
{
    __shared__ float al_s[8 * 100];
    const int b0  = blockIdx.x * 8;
    const int tid = threadIdx.x;
    for (int v = tid; v < 800; v += 256) {
        int r = v / 100, l = v - r * 100;
        al_s[r * 100 + l] = scores[(size_t)l * BB + b0 + r];
    }
    __syncthreads();
    if (tid < 8) {
        float m = -1e30f;
        for (int l = 0; l < LL; ++l) m = fmaxf(m, al_s[tid * 100 + l]);
        float s = 0.f;
        for (int l = 0; l < LL; ++l) { float e = expf(al_s[tid * 100 + l] - m); al_s[tid * 100 + l] = e; s += e; }
        float inv = 1.f / s;
        for (int l = 0; l < LL; ++l) al_s[tid * 100 + l] *= inv;
    }
    __syncthreads();
    float acc[8] = {};
    for (int l = 0; l < LL; ++l) {
        const u16* er = encp + ((size_t)l * BB + b0) * 512 + tid;
        #pragma unroll
        for (int r = 0; r < 8; ++r) acc[r] += al_s[r * 100 + l] * b2f_(er[r * 512]);
    }
    for (int r = 0; r < 8; ++r) ctx[(size_t)(b0 + r) * 256 + tid] = acc[r];
}

// ---------------------------------------------------------------------------
// Decoder LSTM cell: grid 256 x 512, block = 8 rows, half0 = ctx@Wdi,
// half1 = hd@Wdh, coalesced float4 weights. hd updated in place.
// ---------------------------------------------------------------------------
__global__ __launch_bounds__(512) void dec_step(
    const float* __restrict__ ctxp,
    const float* __restrict__ Wdi, const float* __restrict__ Wdh,
    const float* __restrict__ bdec,
    float* __restrict__ hd, float* __restrict__ c_st, int first)
{
    __shared__ float ct_s[8 * 256];        // 8 KB
    __shared__ float hd_s[8 * 256];        // 8 KB
    __shared__ float gate_s[2][8 * 1024];  // 64 KB
    const int row0 = blockIdx.x * 8;
    const int tid  = threadIdx.x;
    const int lane = tid & 63, w = tid >> 6;
    const int half = tid >> 8;
    const int ct   = tid & 255;
    const int c0   = ct * 4;

    ((float4*)ct_s)[tid] = ((const float4*)(ctxp + (size_t)row0 * 256))[tid];
    if (!first)
        ((float4*)hd_s)[tid] = ((const float4*)(hd + (size_t)row0 * 256))[tid];
    __syncthreads();

    float4 acc[8];
    {
        float4 b4 = *(const float4*)&bdec[c0];
        float4 bias4 = (half == 0) ? b4 : make_float4(0.f, 0.f, 0.f, 0.f);
        #pragma unroll
        for (int r = 0; r < 8; ++r) acc[r] = bias4;
    }
    if (half == 0) {
        const float* wP = Wdi + c0;
        #pragma unroll 2
        for (int ch = 0; ch < 64; ++ch) {
            const int k0 = ch * 4;
            float4 w0 = *(const float4*)&wP[(size_t)(k0 + 0) * 1024];
            float4 w1 = *(const float4*)&wP[(size_t)(k0 + 1) * 1024];
            float4 w2 = *(const float4*)&wP[(size_t)(k0 + 2) * 1024];
            float4 w3 = *(const float4*)&wP[(size_t)(k0 + 3) * 1024];
            #pragma unroll
            for (int r = 0; r < 8; ++r) {
                float4 av = *(const float4*)&ct_s[r * 256 + k0];
                acc[r].x += av.x * w0.x; acc[r].y += av.x * w0.y;
                acc[r].z += av.x * w0.z; acc[r].w += av.x * w0.w;
                acc[r].x += av.y * w1.x; acc[r].y += av.y * w1.y;
                acc[r].z += av.y * w1.z; acc[r].w += av.y * w1.w;
                acc[r].x += av.z * w2.x; acc[r].y += av.z * w2.y;
                acc[r].z += av.z * w2.z; acc[r].w += av.z * w2.w;
                acc[r].x += av.w * w3.x; acc[r].y += av.w * w3.y;
                acc[r].z += av.w * w3.z; acc[r].w += av.w * w3.w;
            }
        }
    } else if (!first) {
        const float* wP = Wdh + c0;
        #pragma unroll 2
        for (int ch = 0; ch < 64; ++ch) {
            const int k0 = ch * 4;
            float4 w0 = *(const float4*)&wP[(size_t)(k0 + 0) * 1024];
            float4 w1 = *(const float4*)&wP[(size_t)(k0 + 1) * 1024];
            float4 w2 = *(const float4*)&wP[(size_t)(k0 + 2) * 1024];
            float4 w3 = *(const float4*)&wP[(size_t)(k0 + 3) * 1024];
            #pragma unroll
            for (int r = 0; r < 8; ++r) {
                float4 av = *(const float4*)&hd_s[r * 256 + k0];
                acc[r].x += av.x * w0.x; acc[r].y += av.x * w0.y;
                acc[r].z += av.x * w0.z; acc[r].w += av.x * w0.w;
                acc[r].x += av.y * w1.x; acc[r].y += av.y * w1.y;
                acc[r].z += av.y * w1.z; acc[r].w += av.y * w1.w;
                acc[r].x += av.z * w2.x; acc[r].y += av.z * w2.y;
                acc[r].z += av.z * w2.z; acc[r].w += av.z * w2.w;
                acc[r].x += av.w * w3.x; acc[r].y += av.w * w3.y;
                acc[r].z += av.w * w3.z; acc[r].w += av.w * w3.w;
            }
        }
    }
    #pragma unroll
    for (int r = 0; r < 8; ++r)
        *(float4*)&gate_s[half][r * 1024 + c0] = acc[r];
    __syncthreads();

    {
        const float* g0 = &gate_s[0][w * 1024 + lane * 4];
        const float* g1 = &gate_s[1][w * 1024 + lane * 4];
        float4 giA = *(const float4*)&g0[0],   giB = *(const float4*)&g1[0];
        float4 gfA = *(const float4*)&g0[256], gfB = *(const float4*)&g1[256];
        float4 ggA = *(const float4*)&g0[512], ggB = *(const float4*)&g1[512];
        float4 goA = *(const float4*)&g0[768], goB = *(const float4*)&g1[768];
        size_t ci = (size_t)(row0 + w) * 256 + lane * 4;
        float4 c4 = first ? make_float4(0.f, 0.f, 0.f, 0.f)
                          : *(const float4*)&c_st[ci];
        float cc[4] = { c4.x, c4.y, c4.z, c4.w };
        float gi[4] = { giA.x + giB.x, giA.y + giB.y, giA.z + giB.z, giA.w + giB.w };
        float gf[4] = { gfA.x + gfB.x, gfA.y + gfB.y, gfA.z + gfB.z, gfA.w + gfB.w };
        float gg[4] = { ggA.x + ggB.x, ggA.y + ggB.y, ggA.z + ggB.z, ggA.w + ggB.w };
        float go[4] = { goA.x + goB.x, goA.y + goB.y, goA.z + goB.z, goA.w + goB.w };
        float4 cn, hn;
        #pragma unroll
        for (int uu = 0; uu < 4; ++uu) {
            float cv = sigmoidf_(gf[uu]) * cc[uu] + sigmoidf_(gi[uu]) * tanhf_(gg[uu]);
            float hv = sigmoidf_(go[uu]) * tanhf_(cv);
            if (uu == 0) { cn.x = cv; hn.x = hv; } else if (uu == 1) { cn.y = cv; hn.y = hv; }
            else if (uu == 2) { cn.z = cv; hn.z = hv; } else { cn.w = cv; hn.w = hv; }
        }
        *(float4*)&c_st[ci] = cn;
        *(float4*)&hd[ci]   = hn;
    }
}

// ---------------------------------------------------------------------------
// Head: fc = tanh(h_d@Wf+bf); out[:,step] = tanh(fc@Wo+bo). Block = 16 rows.
// ---------------------------------------------------------------------------
__global__ __launch_bounds__(256) void head_k(
    const float* __restrict__ hd, const float* __restrict__ Wf,
    const float* __restrict__ bf, const float* __restrict__ Wo,
    const float* __restrict__ bo, float* __restrict__ out, int step)
{
    __shared__ float hd_s[16 * 256];
    __shared__ float fc_s[16 * 128];
    const int b0  = blockIdx.x * 16;
    const int tid = threadIdx.x;
    {
        const float4* hg = (const float4*)(hd + (size_t)b0 * 256);
        for (int i = tid; i < 1024; i += 256) ((float4*)hd_s)[i] = hg[i];
    }
    __syncthreads();
    {
        const int f = tid & 127, rg = tid >> 7;
        float acc[8];
        float bfv = bf[f];
        #pragma unroll
        for (int rr = 0; rr < 8; ++rr) acc[rr] = bfv;
        const float* wp = Wf + f;
        #pragma unroll 2
        for (int k = 0; k < 256; ++k) {
            float wv = wp[k * 128];
            #pragma unroll
            for (int rr = 0; rr < 8; ++rr) acc[rr] += hd_s[(rg * 8 + rr) * 256 + k] * wv;
        }
        for (int rr = 0; rr < 8; ++rr) fc_s[(rg * 8 + rr) * 128 + f] = tanhf_(acc[rr]);
    }
    __syncthreads();
    {
        const int lane = tid & 63, w = tid >> 6;
        const float bov = bo[0];
        #pragma unroll
        for (int rr = 0; rr < 4; ++rr) {
            int r = w * 4 + rr;
            float p = fc_s[r * 128 + lane] * Wo[lane] + fc_s[r * 128 + 64 + lane] * Wo[64 + lane];
            #pragma unroll
            for (int msk = 32; msk >= 1; msk >>= 1) p += __shfl_xor(p, msk, 64);
            if (lane == 0) out[(size_t)(b0 + r) * NOUT + step] = tanhf_(p + bov);
        }
    }
}

extern "C" void kernel_launch(void* const* d_in, const int* in_sizes, int n_in,
                              void* d_out, int out_size, void* d_ws, size_t ws_size,
                              hipStream_t stream)
{
    const float* x    = (const float*)d_in[0];
    const float* Wa   = (const float*)d_in[1];
    const float* ba   = (const float*)d_in[2];
    const float* Wi   = (const float*)d_in[3];
    const float* Wh   = (const float*)d_in[4];
    const float* be   = (const float*)d_in[5];
    const float* Wd   = (const float*)d_in[6];
    const float* bd   = (const float*)d_in[7];
    const float* Wl   = (const float*)d_in[8];
    const float* bl   = (const float*)d_in[9];
    const float* Wdi  = (const float*)d_in[10];
    const float* Wdh  = (const float*)d_in[11];
    const float* bdec = (const float*)d_in[12];
    const float* Wf   = (const float*)d_in[13];
    const float* bf   = (const float*)d_in[14];
    const float* Wo   = (const float*)d_in[15];
    const float* bo   = (const float*)d_in[16];
    float* out = (float*)d_out;

    // ws layout (floats): enc_out | hd | c_d | ctx(=hp=wprep alias) | scores | [ep]
    const size_t f_enc    = (size_t)LL * BB * EE;     // 52,428,800
    const size_t f_state  = (size_t)BB * EE;          // 524,288
    const size_t f_scores = (size_t)LL * BB;          // 204,800
    const size_t need3 = (f_enc + 3 * f_state + f_scores) * sizeof(float);
    const size_t need2 = need3 + f_enc * sizeof(u16);
    const size_t need1 = need3 + f_enc * sizeof(float);

    float* ws      = (float*)d_ws;
    float* enc_out = ws;
    float* hd      = enc_out + f_enc;
    float* c_d     = hd + f_state;
    float* ctx     = c_d + f_state;      // also hp AND the encoder weight-prep
    float* scores  = ctx + f_state;      //   buffer (disjoint lifetimes)
    float* ep32    = scores + f_scores;  // tier 1 only
    u16*   ep16    = (u16*)(scores + f_scores);  // tier 2 only
    float* hp      = ctx;
    u16*   wprep   = (u16*)ctx;          // 680 tiles x 1024 u16 = 1.36 MB <= 2 MB
    // encoder h-exchange buffer aliases hd|c_d (4 MB, dead during encoder;
    // decoder step 0 never reads hd/c_d before writing them). flags alias
    // scores (dead during encoder).
    float* hbuf    = hd;
    u32*   flags   = (u32*)scores;

    if (ws_size < need3) return;   // diagnostic clean-fail (known satisfied)
    const int tier = (ws_size >= need1) ? 1 : (ws_size >= need2) ? 2 : 3;

    // zero the group sync counters (re-zeroed on every graph replay)
    hipMemsetAsync(flags, 0, 256, stream);
    // encoder weights -> bf16 hi/lo MFMA fragments (ctx region is dead here)
    w_prep<<<680, 64, 0, stream>>>(Wi, Wh, Wa, wprep);
    // persistent MFMA encoder: 256 blocks (1/CU, all co-resident)
    enc_mfma4<<<256, 1024, 0, stream>>>(x, ba, be, wprep, enc_out, hbuf, flags);

    // hoist the step-invariant enc_out @ Wd_top out of the decode loop
    if (tier == 1)
        gemm_nk256<<<(LL * BB) / 32, 256, 0, stream>>>(
            enc_out, Wd, (const float*)nullptr, ep32, 0);
    else
        pack_ep<<<(LL * BB) / 32, 256, 0, stream>>>(
            enc_out, Wd, ep16, tier == 3 ? 1 : 0);

    for (int s = 0; s < NOUT; ++s) {
        // hp = hd @ Wd_bot + bd  (step 0: hd == 0 -> hp = bd)
        gemm_nk256<<<BB / 32, 256, 0, stream>>>(
            hd, Wd + 256 * 256, bd, hp, s == 0);
        if (tier == 1)
            scores_ep_f32<<<dim3(BB / 8, 5), 256, 0, stream>>>(ep32, hp, Wl, scores);
        else if (tier == 2)
            scores_ep_b16<<<dim3(BB / 8, 5), 256, 0, stream>>>(ep16, hp, Wl, scores, 256, 0);
        else
            scores_ep_b16<<<dim3(BB / 8, 5), 256, 0, stream>>>(
                (const u16*)enc_out, hp, Wl, scores, 512, 256);
        if (tier == 3)
            softmax_ctx_b16<<<BB / 8, 256, 0, stream>>>(scores, (const u16*)enc_out, ctx);
        else
            softmax_ctx<<<BB / 8, 256, 0, stream>>>(scores, enc_out, ctx);
        dec_step<<<BB / 8, 512, 0, stream>>>(ctx, Wdi, Wdh, bdec, hd, c_d, s == 0);
        head_k<<<BB / 16, 256, 0, stream>>>(hd, Wf, bf, Wo, bo, out, s);
    }
}